// Round 3
// baseline (1422.948 us; speedup 1.0000x reference)
//
#include <hip/hip_runtime.h>
#include <hip/hip_bf16.h>

typedef __hip_bfloat16 bf16;
typedef __attribute__((ext_vector_type(8))) short bf16x8;   // 8 bf16 = 4 VGPRs
typedef __attribute__((ext_vector_type(4))) float f32x4;

#define TOK    1024
#define DIM    96
#define HIDN   384
#define HEADS  8
#define DH     768
#define INNER  6144
#define SEQ    512
#define NDEPTH 5
#define EPSLN  1e-5f
#define QSCALE 0.125f

__device__ __forceinline__ float b2f(bf16 v) { return __bfloat162float(v); }
__device__ __forceinline__ bf16  f2b(float v) { return __float2bfloat16(v); }

// Load element i from an external input buffer: f==1 -> bf16, f==0 -> fp32.
__device__ __forceinline__ float gload(const void* p, size_t i, int f) {
  return f ? b2f(((const bf16*)p)[i]) : ((const float*)p)[i];
}
__device__ __forceinline__ const char* gptr(const void* base, size_t off, int f) {
  return (const char*)base + off * (size_t)(f ? 2 : 4);
}

// ---------------- grid-wide barrier (plain launch, no cooperative) ----------
// Sense-reversing barrier: bar[0]=arrive counter, bar[1]=generation.
// Device-scope atomics + __threadfence on both sides handle cross-XCD L2.
__device__ __forceinline__ void gridbar(int* bar) {
  __syncthreads();
  if (threadIdx.x == 0) {
    __threadfence();   // release: publish this block's writes device-wide
    int g = __hip_atomic_load(&bar[1], __ATOMIC_SEQ_CST, __HIP_MEMORY_SCOPE_AGENT);
    int arrived = __hip_atomic_fetch_add(&bar[0], 1, __ATOMIC_SEQ_CST, __HIP_MEMORY_SCOPE_AGENT);
    if (arrived == (int)gridDim.x - 1) {
      __hip_atomic_store(&bar[0], 0, __ATOMIC_SEQ_CST, __HIP_MEMORY_SCOPE_AGENT);
      __hip_atomic_store(&bar[1], g + 1, __ATOMIC_SEQ_CST, __HIP_MEMORY_SCOPE_AGENT);
    } else {
      while (__hip_atomic_load(&bar[1], __ATOMIC_RELAXED, __HIP_MEMORY_SCOPE_AGENT) == g)
        __builtin_amdgcn_s_sleep(2);
    }
    __threadfence();   // acquire: invalidate stale L1/L2 before reading others' data
  }
  __syncthreads();
}

// ---------------- dtype detector (bf16 vs fp32 external buffers) ------------
__global__ __launch_bounds__(256) void detect_kernel(const void* xraw, int* flag,
                                                     int* bar) {
  __shared__ int cnt[256];
  int t = threadIdx.x;
  const unsigned short* u = (const unsigned short*)xraw;
  int c = 0;
  #pragma unroll
  for (int i = 0; i < 4; i++) {
    unsigned short h = u[2 * (t * 4 + i)];
    int e = (h >> 7) & 0xFF;
    if (e >= 87 && e <= 132) c++;
  }
  cnt[t] = c;
  if (t < 2) bar[t] = 0;   // zero grid-barrier state (every graph replay)
  __syncthreads();
  for (int s = 128; s > 0; s >>= 1) {
    if (t < s) cnt[t] += cnt[t + s];
    __syncthreads();
  }
  if (t == 0) *flag = (cnt[0] > 700) ? 1 : 0;
}

// ---------------- cast external weight -> bf16 copy (same layout) -----------
__global__ __launch_bounds__(256) void castw_kernel(const void* __restrict__ in,
                                                    bf16* __restrict__ out, int n,
                                                    const int* __restrict__ flagp) {
  int f = *flagp;
  int i0 = (blockIdx.x * blockDim.x + threadIdx.x) * 4;
  #pragma unroll
  for (int j = 0; j < 4; j++) {
    int i = i0 + j;
    if (i < n) out[i] = f2b(gload(in, i, f));
  }
}

// ---------------- weight transpose+convert: [bz][R][C] -> bf16 [bz][C][R] ---
__global__ __launch_bounds__(256) void wtrans_kernel(
    const void* __restrict__ src, int R, int C,
    bf16* __restrict__ dst, const int* __restrict__ flagp) {
  __shared__ float tile[32][33];
  int f = *flagp;
  int t = threadIdx.x;
  int tx = t & 31, ty = t >> 5;
  int c0 = blockIdx.x * 32, r0 = blockIdx.y * 32;
  size_t bb = (size_t)blockIdx.z * R * C;
  #pragma unroll
  for (int i = 0; i < 4; i++) {
    int r = r0 + ty + 8 * i, c = c0 + tx;
    float v = 0.f;
    if (r < R && c < C) v = gload(src, bb + (size_t)r * C + c, f);
    tile[ty + 8 * i][tx] = v;
  }
  __syncthreads();
  #pragma unroll
  for (int i = 0; i < 4; i++) {
    int cc = c0 + ty + 8 * i, rr = r0 + tx;
    if (cc < C && rr < R)
      dst[bb + (size_t)cc * R + rr] = f2b(tile[tx][ty + 8 * i]);
  }
}

// =================== MFMA GEMM body — BT form (B is bf16 [N][K]) ============
// Used only by mtgt (weight-folding prep). Block 256 = 4 waves (2x2).
template <int WM>
__device__ __forceinline__ void gemm_bt_body(
    const bf16* __restrict__ A, int lda,
    const bf16* __restrict__ Bt, int ldb,
    int m0, int n0, int kbeg, int kend, int Mtot, int N,
    float alpha, bf16* __restrict__ Cb, int ldc) {
  constexpr int TM = WM * 32;
  __shared__ bf16 As[TM][40];
  __shared__ bf16 Bs[128][40];
  int t = threadIdx.x;
  int lane = t & 63;
  int wave = t >> 6;
  int wm = (wave >> 1) * (WM * 16), wn = (wave & 1) * 64;
  f32x4 acc[WM][4];
  #pragma unroll
  for (int i = 0; i < WM; i++)
    #pragma unroll
    for (int j = 0; j < 4; j++) acc[i][j] = (f32x4){0.f, 0.f, 0.f, 0.f};

  int arow = t >> 2, aseg = (t & 3) * 8;

  for (int kb = kbeg; kb < kend; kb += 32) {
    if constexpr (TM >= 64) {
      #pragma unroll
      for (int i = 0; i < TM / 64; i++) {
        int gm = min(m0 + arow + i * 64, Mtot - 1);
        *(uint4*)&As[arow + i * 64][aseg] =
            *(const uint4*)(A + (size_t)gm * lda + kb + aseg);
      }
    } else {
      if (arow < TM) {
        int gm = min(m0 + arow, Mtot - 1);
        *(uint4*)&As[arow][aseg] =
            *(const uint4*)(A + (size_t)gm * lda + kb + aseg);
      }
    }
    #pragma unroll
    for (int i = 0; i < 2; i++) {
      int r = arow + i * 64;
      int gn = n0 + r;
      uint4 val = {0, 0, 0, 0};
      if (gn < N) val = *(const uint4*)(Bt + (size_t)gn * ldb + kb + aseg);
      *(uint4*)&Bs[r][aseg] = val;
    }
    __syncthreads();
    int fm = lane & 15, fq = (lane >> 4) * 8;
    bf16x8 af[WM], bfv[4];
    #pragma unroll
    for (int i = 0; i < WM; i++)
      af[i] = *(const bf16x8*)&As[wm + i * 16 + fm][fq];
    #pragma unroll
    for (int j = 0; j < 4; j++)
      bfv[j] = *(const bf16x8*)&Bs[wn + j * 16 + fm][fq];
    #pragma unroll
    for (int i = 0; i < WM; i++)
      #pragma unroll
      for (int j = 0; j < 4; j++)
        acc[i][j] = __builtin_amdgcn_mfma_f32_16x16x32_bf16(af[i], bfv[j], acc[i][j], 0, 0, 0);
    __syncthreads();
  }
  int col = lane & 15, rq = (lane >> 4) * 4;
  #pragma unroll
  for (int j = 0; j < 4; j++) {
    int gn = n0 + wn + j * 16 + col;
    if (gn >= N) continue;
    #pragma unroll
    for (int i = 0; i < WM; i++) {
      #pragma unroll
      for (int r = 0; r < 4; r++) {
        int gm = m0 + wm + i * 16 + rq + r;
        if (gm >= Mtot) continue;
        Cb[(size_t)gm * ldc + gn] = f2b(acc[i][j][r] * alpha);
      }
    }
  }
}

// ---- precompute Mt (z<120) and Gt (z>=120): grid (1, 2, 240) ---------------
__global__ __launch_bounds__(256) void mtgt_kernel(
    const bf16* __restrict__ wqB, const bf16* __restrict__ wkB,
    const bf16* __restrict__ wvB, const bf16* __restrict__ woT,
    bf16* __restrict__ Mt, bf16* __restrict__ Gt) {
  int z = blockIdx.z;
  bool isM = z < 120;
  int zz = isM ? z : z - 120;
  int L = zz >> 3, h = zz & 7;
  size_t wo = (size_t)L * DIM * INNER + (size_t)h * DH;
  const bf16* A  = isM ? (wkB + wo) : (woT + wo);
  const bf16* Bt = isM ? (wqB + wo) : (wvB + wo);
  bf16* C = (isM ? Mt : Gt) + (size_t)zz * DIM * DIM;
  gemm_bt_body<2>(A, INNER, Bt, INNER, blockIdx.y * 64, 0, 0, DH, DIM, DIM,
                  isM ? QSCALE : 1.f, C, DIM);
}

// ===================== mega-kernel LDS layouts (aliased) ====================
struct AttnLds { bf16 tP[32][520]; bf16 Zs[32][104]; float red[2][4][32]; };
struct MlpLds  { float X1s[32][96]; bf16 As[32][104]; bf16 Hs[32][392]; };
#define LDS_BYTES (sizeof(MlpLds) > sizeof(AttnLds) ? sizeof(MlpLds) : sizeof(AttnLds))

// ---- per-row LayerNorm helper: one wave, row of 96 (v1 valid for lane<32) --
__device__ __forceinline__ void ln_row_vals(float v0, float v1in, int lane,
    const char* g, int f, float& o0, float& o1) {
  float v1 = (lane < 32) ? v1in : 0.f;
  float s = v0 + v1;
  #pragma unroll
  for (int off = 32; off > 0; off >>= 1) s += __shfl_xor(s, off);
  float mu = s * (1.f / 96.f);
  float d0 = v0 - mu;
  float d1 = (lane < 32) ? (v1 - mu) : 0.f;
  float q = d0 * d0 + d1 * d1;
  #pragma unroll
  for (int off = 32; off > 0; off >>= 1) q += __shfl_xor(q, off);
  float rstd = rsqrtf(q * (1.f / 96.f) + EPSLN);
  o0 = d0 * rstd * (gload(g, lane, f) + 1.f);
  o1 = (lane < 32) ? (d1 * rstd * (gload(g, 64 + lane, f) + 1.f)) : 0.f;
}

__device__ __forceinline__ void store_hn(bf16* hn, bf16* hnT, int row, int lane,
                                         float o0, float o1) {
  size_t base = (size_t)row * DIM;
  bf16* hT = hnT + (size_t)(row >> 9) * DIM * SEQ;
  int ss = row & (SEQ - 1);
  hn[base + lane] = f2b(o0);
  hT[(size_t)lane * SEQ + ss] = f2b(o0);
  if (lane < 32) {
    hn[base + 64 + lane] = f2b(o1);
    hT[(size_t)(64 + lane) * SEQ + ss] = f2b(o1);
  }
}

// ---- stage: cast input + LN0 (4 rows per block) ----------------------------
__device__ __forceinline__ void castln_stage(const void* in_x, float* x,
    bf16* hn, bf16* hnT, const void* gb, size_t goff, int f, int bid) {
  int wave = threadIdx.x >> 6, lane = threadIdx.x & 63;
  int row = bid * 4 + wave;
  size_t base = (size_t)row * DIM;
  float v0 = gload(in_x, base + lane, f);
  float v1 = (lane < 32) ? gload(in_x, base + 64 + lane, f) : 0.f;
  x[base + lane] = v0;
  if (lane < 32) x[base + 64 + lane] = v1;
  float o0, o1;
  ln_row_vals(v0, v1, lane, gptr(gb, goff, f), f, o0, o1);
  store_hn(hn, hnT, row, lane, o0, o1);
}

// ---- stage: LN of x (4 rows per block) -------------------------------------
__device__ __forceinline__ void ln_stage(const float* x, bf16* hn, bf16* hnT,
    const void* gb, size_t goff, int f, int bid) {
  int wave = threadIdx.x >> 6, lane = threadIdx.x & 63;
  int row = bid * 4 + wave;
  size_t base = (size_t)row * DIM;
  float v0 = x[base + lane];
  float v1 = (lane < 32) ? x[base + 64 + lane] : 0.f;
  float o0, o1;
  ln_row_vals(v0, v1, lane, gptr(gb, goff, f), f, o0, o1);
  store_hn(hn, hnT, row, lane, o0, o1);
}

// ---- stage: fused attention (verbatim port of round-1 fattn3_kernel) -------
__device__ void fattn_stage(char* ldsraw,
    const bf16* __restrict__ hn, const bf16* __restrict__ hnT,
    const bf16* __restrict__ MtL, const bf16* __restrict__ GtL,
    float* __restrict__ x, int bid) {
  AttnLds& L = *reinterpret_cast<AttnLds*>(ldsraw);
  int tid = threadIdx.x, lane = tid & 63, wave = tid >> 6;
  int fm = lane & 15, fq = (lane >> 4) * 8;
  int col = lane & 15, rq = (lane >> 4) * 4;
  int mw = wave & 1, ng = wave >> 1;
  int z = bid >> 4, b = z >> 3, h = z & 7;
  int m0 = (bid & 15) * 32;
  const bf16* hnB = hn + (size_t)b * SEQ * DIM;
  const bf16* hTB = hnT + (size_t)b * DIM * SEQ;
  const bf16* MtH = MtL + (size_t)h * DIM * DIM;
  const bf16* GtH = GtL + (size_t)h * DIM * DIM;

  // ---- stage 1: t = hn_tile[32x96] @ Mt^T ----
  {
    f32x4 acc1[3];
    #pragma unroll
    for (int j = 0; j < 3; j++) acc1[j] = (f32x4){0.f, 0.f, 0.f, 0.f};
    #pragma unroll
    for (int kb = 0; kb < 96; kb += 32) {
      bf16x8 af = *(const bf16x8*)(hnB + (size_t)(m0 + mw * 16 + fm) * DIM + kb + fq);
      #pragma unroll
      for (int j = 0; j < 3; j++) {
        bf16x8 bv = *(const bf16x8*)(MtH + (size_t)((3 * ng + j) * 16 + fm) * DIM + kb + fq);
        acc1[j] = __builtin_amdgcn_mfma_f32_16x16x32_bf16(af, bv, acc1[j], 0, 0, 0);
      }
    }
    #pragma unroll
    for (int j = 0; j < 3; j++)
      #pragma unroll
      for (int r = 0; r < 4; r++)
        L.Zs[mw * 16 + rq + r][(3 * ng + j) * 16 + col] = f2b(acc1[j][r]);
  }
  __syncthreads();

  // ---- stage 2: S = t @ hn^T (32 x 512); wave covers cols [128w,128w+128) --
  f32x4 acc2[2][8];
  #pragma unroll
  for (int i = 0; i < 2; i++)
    #pragma unroll
    for (int j = 0; j < 8; j++) acc2[i][j] = (f32x4){0.f, 0.f, 0.f, 0.f};
  #pragma unroll
  for (int kb = 0; kb < 96; kb += 32) {
    bf16x8 af0 = *(const bf16x8*)&L.Zs[fm][kb + fq];
    bf16x8 af1 = *(const bf16x8*)&L.Zs[16 + fm][kb + fq];
    bf16x8 bv[8];
    #pragma unroll
    for (int j = 0; j < 8; j++)
      bv[j] = *(const bf16x8*)(hnB + (size_t)(wave * 128 + j * 16 + fm) * DIM + kb + fq);
    #pragma unroll
    for (int j = 0; j < 8; j++) {
      acc2[0][j] = __builtin_amdgcn_mfma_f32_16x16x32_bf16(af0, bv[j], acc2[0][j], 0, 0, 0);
      acc2[1][j] = __builtin_amdgcn_mfma_f32_16x16x32_bf16(af1, bv[j], acc2[1][j], 0, 0, 0);
    }
  }

  // ---- softmax over 512 cols ----
  float rmax[2][4];
  #pragma unroll
  for (int i = 0; i < 2; i++)
    #pragma unroll
    for (int r = 0; r < 4; r++) {
      float m = -1e30f;
      #pragma unroll
      for (int j = 0; j < 8; j++) m = fmaxf(m, acc2[i][j][r]);
      rmax[i][r] = m;
    }
  #pragma unroll
  for (int s = 1; s < 16; s <<= 1)
    #pragma unroll
    for (int i = 0; i < 2; i++)
      #pragma unroll
      for (int r = 0; r < 4; r++)
        rmax[i][r] = fmaxf(rmax[i][r], __shfl_xor(rmax[i][r], s));
  if (col == 0)
    #pragma unroll
    for (int i = 0; i < 2; i++)
      #pragma unroll
      for (int r = 0; r < 4; r++) L.red[0][wave][i * 16 + rq + r] = rmax[i][r];
  __syncthreads();
  float rsum[2][4];
  #pragma unroll
  for (int i = 0; i < 2; i++)
    #pragma unroll
    for (int r = 0; r < 4; r++) {
      int row = i * 16 + rq + r;
      float gm = fmaxf(fmaxf(L.red[0][0][row], L.red[0][1][row]),
                       fmaxf(L.red[0][2][row], L.red[0][3][row]));
      float s = 0.f;
      #pragma unroll
      for (int j = 0; j < 8; j++) {
        float e = __expf(acc2[i][j][r] - gm);
        acc2[i][j][r] = e;
        s += e;
      }
      rsum[i][r] = s;
    }
  #pragma unroll
  for (int s = 1; s < 16; s <<= 1)
    #pragma unroll
    for (int i = 0; i < 2; i++)
      #pragma unroll
      for (int r = 0; r < 4; r++)
        rsum[i][r] += __shfl_xor(rsum[i][r], s);
  if (col == 0)
    #pragma unroll
    for (int i = 0; i < 2; i++)
      #pragma unroll
      for (int r = 0; r < 4; r++) L.red[1][wave][i * 16 + rq + r] = rsum[i][r];
  __syncthreads();

  // each wave writes its own normalized 128-col P chunk
  #pragma unroll
  for (int i = 0; i < 2; i++)
    #pragma unroll
    for (int r = 0; r < 4; r++) {
      int row = i * 16 + rq + r;
      float tot = L.red[1][0][row] + L.red[1][1][row] + L.red[1][2][row] + L.red[1][3][row];
      float inv = 1.f / tot;
      #pragma unroll
      for (int j = 0; j < 8; j++)
        L.tP[row][wave * 128 + j * 16 + col] = f2b(acc2[i][j][r] * inv);
    }
  __syncthreads();

  // ---- stage 3a: Z = P @ hnT^T (32 x 96), K = 512 ----
  f32x4 acc3[3];
  #pragma unroll
  for (int j = 0; j < 3; j++) acc3[j] = (f32x4){0.f, 0.f, 0.f, 0.f};
  #pragma unroll 4
  for (int kb = 0; kb < 512; kb += 32) {
    bf16x8 af = *(const bf16x8*)&L.tP[mw * 16 + fm][kb + fq];
    #pragma unroll
    for (int j = 0; j < 3; j++) {
      bf16x8 bv = *(const bf16x8*)(hTB + (size_t)((3 * ng + j) * 16 + fm) * SEQ + kb + fq);
      acc3[j] = __builtin_amdgcn_mfma_f32_16x16x32_bf16(af, bv, acc3[j], 0, 0, 0);
    }
  }
  __syncthreads();   // t in Zs dead; safe to overwrite
  #pragma unroll
  for (int j = 0; j < 3; j++)
    #pragma unroll
    for (int r = 0; r < 4; r++)
      L.Zs[mw * 16 + rq + r][(3 * ng + j) * 16 + col] = f2b(acc3[j][r]);
  __syncthreads();

  // ---- stage 3b: O = Z @ Gt^T (32 x 96), K = 96 ----
  f32x4 acc4[3];
  #pragma unroll
  for (int j = 0; j < 3; j++) acc4[j] = (f32x4){0.f, 0.f, 0.f, 0.f};
  #pragma unroll
  for (int kb = 0; kb < 96; kb += 32) {
    bf16x8 af = *(const bf16x8*)&L.Zs[mw * 16 + fm][kb + fq];
    #pragma unroll
    for (int j = 0; j < 3; j++) {
      bf16x8 bv = *(const bf16x8*)(GtH + (size_t)((3 * ng + j) * 16 + fm) * DIM + kb + fq);
      acc4[j] = __builtin_amdgcn_mfma_f32_16x16x32_bf16(af, bv, acc4[j], 0, 0, 0);
    }
  }
  #pragma unroll
  for (int j = 0; j < 3; j++) {
    int gn = (3 * ng + j) * 16 + col;
    #pragma unroll
    for (int r = 0; r < 4; r++) {
      int gr = b * SEQ + m0 + mw * 16 + rq + r;
      atomicAdd(x + (size_t)gr * DIM + gn, acc4[j][r]);
    }
  }
}

// ---- stage: fused MLP + fused LN epilogue ----------------------------------
// lnmode 1: epilogue writes hn/hnT with gamma (lngb+lngoff).
// lnmode 2: epilogue writes final LN to dout (fp32 if f==0 else bf16).
__device__ void fmlp_stage(char* ldsraw, float* __restrict__ X,
    const void* __restrict__ gmidb, size_t gmidoff, int useMid,
    const void* __restrict__ gmb, size_t gmoff,
    const bf16* __restrict__ w1T, const void* __restrict__ b1b, size_t b1off,
    const bf16* __restrict__ w2T, const void* __restrict__ b2b, size_t b2off,
    int f, int bid,
    int lnmode, const void* __restrict__ lngb, size_t lngoff,
    bf16* __restrict__ hn, bf16* __restrict__ hnT, void* __restrict__ dout) {
  if (bid >= 32) return;
  MlpLds& L = *reinterpret_cast<MlpLds*>(ldsraw);
  int tid = threadIdx.x, lane = tid & 63, wave = tid >> 6;
  int fm = lane & 15, fq = (lane >> 4) * 8;
  int col = lane & 15, rq = (lane >> 4) * 4;
  int m0 = bid * 32;
  const char* gm = gptr(gmb, gmoff, f);
  float gm0 = gload(gm, lane, f) + 1.f;
  float gm1 = (lane < 32) ? (gload(gm, 64 + lane, f) + 1.f) : 0.f;
  float gd0 = 1.f, gd1 = 1.f;
  if (useMid) {
    const char* gmid = gptr(gmidb, gmidoff, f);
    gd0 = gload(gmid, lane, f) + 1.f;
    gd1 = (lane < 32) ? (gload(gmid, 64 + lane, f) + 1.f) : 0.f;
  }
  for (int r = wave; r < 32; r += 4) {
    const float* xr = X + (size_t)(m0 + r) * DIM;
    float v0 = xr[lane];
    float v1 = (lane < 32) ? xr[64 + lane] : 0.f;
    if (useMid) {
      float s = v0 + v1;
      #pragma unroll
      for (int off = 32; off > 0; off >>= 1) s += __shfl_xor(s, off);
      float mu = s * (1.f / 96.f);
      float d0 = v0 - mu;
      float d1 = (lane < 32) ? (v1 - mu) : 0.f;
      float q = d0 * d0 + d1 * d1;
      #pragma unroll
      for (int off = 32; off > 0; off >>= 1) q += __shfl_xor(q, off);
      float rstd = rsqrtf(q * (1.f / 96.f) + EPSLN);
      v0 = d0 * rstd * gd0;
      v1 = (lane < 32) ? (d1 * rstd * gd1) : 0.f;
    }
    L.X1s[r][lane] = v0;
    if (lane < 32) L.X1s[r][64 + lane] = v1;
    float s = v0 + v1;
    #pragma unroll
    for (int off = 32; off > 0; off >>= 1) s += __shfl_xor(s, off);
    float mu = s * (1.f / 96.f);
    float d0 = v0 - mu;
    float d1 = (lane < 32) ? (v1 - mu) : 0.f;
    float q = d0 * d0 + d1 * d1;
    #pragma unroll
    for (int off = 32; off > 0; off >>= 1) q += __shfl_xor(q, off);
    float rstd = rsqrtf(q * (1.f / 96.f) + EPSLN);
    L.As[r][lane] = f2b(d0 * rstd * gm0);
    if (lane < 32) L.As[r][64 + lane] = f2b(d1 * rstd * gm1);
  }
  __syncthreads();

  // ---- GEMM1: [32x96] @ W1 -> [32x384], bias + exact GELU ----
  int mw = wave & 1, nh = wave >> 1;
  f32x4 acc1[12];
  #pragma unroll
  for (int j = 0; j < 12; j++) acc1[j] = (f32x4){0.f, 0.f, 0.f, 0.f};
  #pragma unroll
  for (int kb = 0; kb < 96; kb += 32) {
    bf16x8 af = *(const bf16x8*)&L.As[mw * 16 + fm][kb + fq];
    #pragma unroll
    for (int j = 0; j < 12; j++) {
      bf16x8 bv = *(const bf16x8*)(w1T + (size_t)(nh * 192 + j * 16 + fm) * DIM + kb + fq);
      acc1[j] = __builtin_amdgcn_mfma_f32_16x16x32_bf16(af, bv, acc1[j], 0, 0, 0);
    }
  }
  const char* b1p = gptr(b1b, b1off, f);
  #pragma unroll
  for (int j = 0; j < 12; j++) {
    int gn = nh * 192 + j * 16 + col;
    float bv = gload(b1p, gn, f);
    #pragma unroll
    for (int r = 0; r < 4; r++) {
      float v = acc1[j][r] + bv;
      v = 0.5f * v * (1.f + erff(v * 0.70710678118f));
      L.Hs[mw * 16 + rq + r][gn] = f2b(v);
    }
  }
  __syncthreads();

  // ---- GEMM2: [32x384] @ W2 -> [32x96], bias + residual, store X ----
  int ng = wave >> 1;
  f32x4 acc2[3];
  #pragma unroll
  for (int j = 0; j < 3; j++) acc2[j] = (f32x4){0.f, 0.f, 0.f, 0.f};
  #pragma unroll 4
  for (int kb = 0; kb < 384; kb += 32) {
    bf16x8 af = *(const bf16x8*)&L.Hs[mw * 16 + fm][kb + fq];
    #pragma unroll
    for (int j = 0; j < 3; j++) {
      bf16x8 bv = *(const bf16x8*)(w2T + (size_t)((3 * ng + j) * 16 + fm) * HIDN + kb + fq);
      acc2[j] = __builtin_amdgcn_mfma_f32_16x16x32_bf16(af, bv, acc2[j], 0, 0, 0);
    }
  }
  const char* b2p = gptr(b2b, b2off, f);
  #pragma unroll
  for (int j = 0; j < 3; j++) {
    int gn = (3 * ng + j) * 16 + col;
    float bb = gload(b2p, gn, f);
    #pragma unroll
    for (int r = 0; r < 4; r++) {
      int gmr = m0 + mw * 16 + rq + r;
      X[(size_t)gmr * DIM + gn] = L.X1s[mw * 16 + rq + r][gn] + acc2[j][r] + bb;
    }
  }
  __syncthreads();

  // ---- fused LN epilogue over this block's 32 rows ----
  const char* lg = gptr(lngb, lngoff, f);
  for (int r = wave; r < 32; r += 4) {
    int row = m0 + r;
    size_t base = (size_t)row * DIM;
    float v0 = X[base + lane];
    float v1 = (lane < 32) ? X[base + 64 + lane] : 0.f;
    float o0, o1;
    ln_row_vals(v0, v1, lane, lg, f, o0, o1);
    if (lnmode == 1) {
      store_hn(hn, hnT, row, lane, o0, o1);
    } else {
      if (!f) {
        ((float*)dout)[base + lane] = o0;
        if (lane < 32) ((float*)dout)[base + 64 + lane] = o1;
      } else {
        ((bf16*)dout)[base + lane] = f2b(o0);
        if (lane < 32) ((bf16*)dout)[base + 64 + lane] = f2b(o1);
      }
    }
  }
}

// ===================== the mega-kernel (plain launch + gridbar) =============
__global__ void __launch_bounds__(256, 1) mega_kernel(
    const void* __restrict__ in_x, float* __restrict__ x,
    bf16* __restrict__ hn, bf16* __restrict__ hnT,
    const bf16* __restrict__ Mt, const bf16* __restrict__ Gt,
    const bf16* __restrict__ w1T, const bf16* __restrict__ w2T,
    const void* __restrict__ gam_a, const void* __restrict__ gam_m,
    const void* __restrict__ gam_mid, const void* __restrict__ gam_fin,
    const void* __restrict__ b1, const void* __restrict__ b2,
    void* __restrict__ dout, const int* __restrict__ flagp,
    int* __restrict__ bar) {
  __shared__ __align__(16) char lds[LDS_BYTES];
  int f = *flagp;
  int bid = blockIdx.x;

  // stage 0: cast input + LN(gam_a[0,0]) -> hn, hnT
  castln_stage(in_x, x, hn, hnT, gam_a, 0, f, bid);
  gridbar(bar);

  for (int d = 0; d < NDEPTH; d++) {
    size_t ga1 = (size_t)(d * 3 + 1) * DIM;
    size_t ga2 = (size_t)(d * 3 + 2) * DIM;
    const bf16* Mt0 = Mt + (size_t)(d * 3 + 0) * 8 * DIM * DIM;
    const bf16* Gt0 = Gt + (size_t)(d * 3 + 0) * 8 * DIM * DIM;
    const bf16* Mt1 = Mt + (size_t)(d * 3 + 1) * 8 * DIM * DIM;
    const bf16* Gt1 = Gt + (size_t)(d * 3 + 1) * 8 * DIM * DIM;
    const bf16* Mt2 = Mt + (size_t)(d * 3 + 2) * 8 * DIM * DIM;
    const bf16* Gt2 = Gt + (size_t)(d * 3 + 2) * 8 * DIM * DIM;

    fattn_stage(lds, hn, hnT, Mt0, Gt0, x, bid);
    gridbar(bar);

    // mlp0 + fused LN(gam_a[d,1])
    fmlp_stage(lds, x, nullptr, 0, 0,
               gam_m, (size_t)(d * 2 + 0) * DIM,
               w1T + (size_t)(d * 2 + 0) * DIM * HIDN, b1, (size_t)(d * 2 + 0) * HIDN,
               w2T + (size_t)(d * 2 + 0) * DIM * HIDN, b2, (size_t)(d * 2 + 0) * DIM,
               f, bid, 1, gam_a, ga1, hn, hnT, nullptr);
    gridbar(bar);

    fattn_stage(lds, hn, hnT, Mt1, Gt1, x, bid);
    gridbar(bar);

    ln_stage(x, hn, hnT, gam_a, ga2, f, bid);
    gridbar(bar);

    fattn_stage(lds, hn, hnT, Mt2, Gt2, x, bid);
    gridbar(bar);

    bool last = (d == NDEPTH - 1);
    // mlp1 (includes bare mid-LN) + fused LN: next-depth gam_a[.,0] or final
    fmlp_stage(lds, x, gam_mid, (size_t)d * DIM, 1,
               gam_m, (size_t)(d * 2 + 1) * DIM,
               w1T + (size_t)(d * 2 + 1) * DIM * HIDN, b1, (size_t)(d * 2 + 1) * HIDN,
               w2T + (size_t)(d * 2 + 1) * DIM * HIDN, b2, (size_t)(d * 2 + 1) * DIM,
               f, bid,
               last ? 2 : 1, last ? gam_fin : gam_a,
               last ? (size_t)0 : (size_t)((d + 1) * 3) * DIM,
               hn, hnT, dout);
    if (!last) gridbar(bar);
  }
}

// ---------------- host-side orchestration ----------------
extern "C" void kernel_launch(void* const* d_in, const int* in_sizes, int n_in,
                              void* d_out, int out_size, void* d_ws, size_t ws_size,
                              hipStream_t stream) {
  const void* in_x    = d_in[0];
  const void* gam_a   = d_in[1];
  const void* Wq      = d_in[2];
  const void* Wk      = d_in[3];
  const void* Wv      = d_in[4];
  const void* Wo      = d_in[5];
  const void* gam_m   = d_in[6];
  const void* W1      = d_in[7];
  const void* b1      = d_in[8];
  const void* W2      = d_in[9];
  const void* b2      = d_in[10];
  const void* gam_mid = d_in[11];
  const void* gam_fin = d_in[12];

  char* wsb = (char*)d_ws;
  size_t off = 0;
  auto carve = [&](size_t bytes) {
    char* p = wsb + off;
    off += (bytes + 255) & ~(size_t)255;
    return p;
  };
  int*   flag = (int*)carve(256);
  int*   bar  = (int*)carve(256);
  float* x    = (float*)carve((size_t)TOK * DIM * 4);
  bf16*  hn   = (bf16*)carve((size_t)TOK * DIM * 2);
  bf16*  hnT  = (bf16*)carve((size_t)2 * DIM * SEQ * 2);
  const size_t WSZ = (size_t)15 * DIM * INNER;   // per big weight, elements
  bf16*  wqB  = (bf16*)carve(WSZ * 2);
  bf16*  wkB  = (bf16*)carve(WSZ * 2);
  bf16*  wvB  = (bf16*)carve(WSZ * 2);
  bf16*  woT  = (bf16*)carve(WSZ * 2);
  bf16*  w1T  = (bf16*)carve((size_t)10 * DIM * HIDN * 2);
  bf16*  w2T  = (bf16*)carve((size_t)10 * DIM * HIDN * 2);
  bf16*  Mt   = (bf16*)carve((size_t)120 * DIM * DIM * 2);
  bf16*  Gt   = (bf16*)carve((size_t)120 * DIM * DIM * 2);

  detect_kernel<<<dim3(1), dim3(256), 0, stream>>>(in_x, flag, bar);

  // ---- once-per-call weight prep ----
  int nW = (int)WSZ;
  castw_kernel<<<dim3((nW / 4 + 255) / 256), dim3(256), 0, stream>>>(Wq, wqB, nW, flag);
  castw_kernel<<<dim3((nW / 4 + 255) / 256), dim3(256), 0, stream>>>(Wk, wkB, nW, flag);
  castw_kernel<<<dim3((nW / 4 + 255) / 256), dim3(256), 0, stream>>>(Wv, wvB, nW, flag);
  wtrans_kernel<<<dim3(3, 192, 15), dim3(256), 0, stream>>>(Wo, INNER, DIM, woT, flag);
  wtrans_kernel<<<dim3(12, 3, 10), dim3(256), 0, stream>>>(W1, DIM, HIDN, w1T, flag);
  wtrans_kernel<<<dim3(3, 12, 10), dim3(256), 0, stream>>>(W2, HIDN, DIM, w2T, flag);
  mtgt_kernel<<<dim3(1, 2, 240), dim3(256), 0, stream>>>(wqB, wkB, wvB, woT, Mt, Gt);

  // ---- single persistent mega-kernel for the whole depth loop ----
  mega_kernel<<<dim3(256), dim3(256), 0, stream>>>(
      in_x, x, hn, hnT, Mt, Gt, w1T, w2T,
      gam_a, gam_m, gam_mid, gam_fin, b1, b2, d_out, flag, bar);
}

// Round 4
// 703.151 us; speedup vs baseline: 2.0237x; 2.0237x over previous
//
#include <hip/hip_runtime.h>
#include <hip/hip_bf16.h>

typedef __hip_bfloat16 bf16;
typedef __attribute__((ext_vector_type(8))) short bf16x8;   // 8 bf16 = 4 VGPRs
typedef __attribute__((ext_vector_type(4))) float f32x4;

#define TOK    1024
#define DIM    96
#define HIDN   384
#define HEADS  8
#define DH     768
#define INNER  6144
#define SEQ    512
#define NDEPTH 5
#define EPSLN  1e-5f
#define QSCALE 0.125f

#define MFMA16(a, b, c) __builtin_amdgcn_mfma_f32_16x16x32_bf16((a), (b), (c), 0, 0, 0)

__device__ __forceinline__ float b2f(bf16 v) { return __bfloat162float(v); }
__device__ __forceinline__ bf16  f2b(float v) { return __float2bfloat16(v); }

// Load element i from an external input buffer: f==1 -> bf16, f==0 -> fp32.
__device__ __forceinline__ float gload(const void* p, size_t i, int f) {
  return f ? b2f(((const bf16*)p)[i]) : ((const float*)p)[i];
}
__device__ __forceinline__ const char* gptr(const void* base, size_t off, int f) {
  return (const char*)base + off * (size_t)(f ? 2 : 4);
}

// ---------------- dtype detector (bf16 vs fp32 external buffers) ------------
__global__ __launch_bounds__(256) void detect_kernel(const void* xraw, int* flag) {
  __shared__ int cnt[256];
  int t = threadIdx.x;
  const unsigned short* u = (const unsigned short*)xraw;
  int c = 0;
  #pragma unroll
  for (int i = 0; i < 4; i++) {
    unsigned short h = u[2 * (t * 4 + i)];
    int e = (h >> 7) & 0xFF;
    if (e >= 87 && e <= 132) c++;
  }
  cnt[t] = c;
  __syncthreads();
  for (int s = 128; s > 0; s >>= 1) {
    if (t < s) cnt[t] += cnt[t + s];
    __syncthreads();
  }
  if (t == 0) *flag = (cnt[0] > 700) ? 1 : 0;
}

// ------- cast 3 external weights -> bf16 copies (z selects the weight) ------
__global__ __launch_bounds__(256) void castw3_kernel(
    const void* __restrict__ w0, const void* __restrict__ w1,
    const void* __restrict__ w2, bf16* __restrict__ o0,
    bf16* __restrict__ o1, bf16* __restrict__ o2, int n,
    const int* __restrict__ flagp) {
  int f = *flagp;
  const void* in = (blockIdx.y == 0) ? w0 : (blockIdx.y == 1) ? w1 : w2;
  bf16* out = (blockIdx.y == 0) ? o0 : (blockIdx.y == 1) ? o1 : o2;
  int i0 = (blockIdx.x * blockDim.x + threadIdx.x) * 4;
  #pragma unroll
  for (int j = 0; j < 4; j++) {
    int i = i0 + j;
    if (i < n) out[i] = f2b(gload(in, i, f));
  }
}

// ---------------- weight transpose+convert: [bz][R][C] -> bf16 [bz][C][R] ---
__global__ __launch_bounds__(256) void wtrans_kernel(
    const void* __restrict__ src, int R, int C,
    bf16* __restrict__ dst, const int* __restrict__ flagp) {
  __shared__ float tile[32][33];
  int f = *flagp;
  int t = threadIdx.x;
  int tx = t & 31, ty = t >> 5;
  int c0 = blockIdx.x * 32, r0 = blockIdx.y * 32;
  size_t bb = (size_t)blockIdx.z * R * C;
  #pragma unroll
  for (int i = 0; i < 4; i++) {
    int r = r0 + ty + 8 * i, c = c0 + tx;
    float v = 0.f;
    if (r < R && c < C) v = gload(src, bb + (size_t)r * C + c, f);
    tile[ty + 8 * i][tx] = v;
  }
  __syncthreads();
  #pragma unroll
  for (int i = 0; i < 4; i++) {
    int cc = c0 + ty + 8 * i, rr = r0 + tx;
    if (cc < C && rr < R)
      dst[bb + (size_t)cc * R + rr] = f2b(tile[tx][ty + 8 * i]);
  }
}

// =================== MFMA GEMM body — BT form (B is bf16 [N][K]) ============
// Used only by mtgt (weight-folding prep). Block 256 = 4 waves (2x2).
template <int WM>
__device__ __forceinline__ void gemm_bt_body(
    const bf16* __restrict__ A, int lda,
    const bf16* __restrict__ Bt, int ldb,
    int m0, int n0, int kbeg, int kend, int Mtot, int N,
    float alpha, bf16* __restrict__ Cb, int ldc) {
  constexpr int TM = WM * 32;
  __shared__ bf16 As[TM][40];
  __shared__ bf16 Bs[128][40];
  int t = threadIdx.x;
  int lane = t & 63;
  int wave = t >> 6;
  int wm = (wave >> 1) * (WM * 16), wn = (wave & 1) * 64;
  f32x4 acc[WM][4];
  #pragma unroll
  for (int i = 0; i < WM; i++)
    #pragma unroll
    for (int j = 0; j < 4; j++) acc[i][j] = (f32x4){0.f, 0.f, 0.f, 0.f};

  int arow = t >> 2, aseg = (t & 3) * 8;

  for (int kb = kbeg; kb < kend; kb += 32) {
    if constexpr (TM >= 64) {
      #pragma unroll
      for (int i = 0; i < TM / 64; i++) {
        int gm = min(m0 + arow + i * 64, Mtot - 1);
        *(uint4*)&As[arow + i * 64][aseg] =
            *(const uint4*)(A + (size_t)gm * lda + kb + aseg);
      }
    } else {
      if (arow < TM) {
        int gm = min(m0 + arow, Mtot - 1);
        *(uint4*)&As[arow][aseg] =
            *(const uint4*)(A + (size_t)gm * lda + kb + aseg);
      }
    }
    #pragma unroll
    for (int i = 0; i < 2; i++) {
      int r = arow + i * 64;
      int gn = n0 + r;
      uint4 val = {0, 0, 0, 0};
      if (gn < N) val = *(const uint4*)(Bt + (size_t)gn * ldb + kb + aseg);
      *(uint4*)&Bs[r][aseg] = val;
    }
    __syncthreads();
    int fm = lane & 15, fq = (lane >> 4) * 8;
    bf16x8 af[WM], bfv[4];
    #pragma unroll
    for (int i = 0; i < WM; i++)
      af[i] = *(const bf16x8*)&As[wm + i * 16 + fm][fq];
    #pragma unroll
    for (int j = 0; j < 4; j++)
      bfv[j] = *(const bf16x8*)&Bs[wn + j * 16 + fm][fq];
    #pragma unroll
    for (int i = 0; i < WM; i++)
      #pragma unroll
      for (int j = 0; j < 4; j++)
        acc[i][j] = MFMA16(af[i], bfv[j], acc[i][j]);
    __syncthreads();
  }
  int col = lane & 15, rq = (lane >> 4) * 4;
  #pragma unroll
  for (int j = 0; j < 4; j++) {
    int gn = n0 + wn + j * 16 + col;
    if (gn >= N) continue;
    #pragma unroll
    for (int i = 0; i < WM; i++) {
      #pragma unroll
      for (int r = 0; r < 4; r++) {
        int gm = m0 + wm + i * 16 + rq + r;
        if (gm >= Mtot) continue;
        Cb[(size_t)gm * ldc + gn] = f2b(acc[i][j][r] * alpha);
      }
    }
  }
}

// ---- precompute Mt (z<120) and Gt (z>=120): grid (1, 2, 240) ---------------
__global__ __launch_bounds__(256) void mtgt_kernel(
    const bf16* __restrict__ wqB, const bf16* __restrict__ wkB,
    const bf16* __restrict__ wvB, const bf16* __restrict__ woT,
    bf16* __restrict__ Mt, bf16* __restrict__ Gt) {
  int z = blockIdx.z;
  bool isM = z < 120;
  int zz = isM ? z : z - 120;
  int L = zz >> 3, h = zz & 7;
  size_t wo = (size_t)L * DIM * INNER + (size_t)h * DH;
  const bf16* A  = isM ? (wkB + wo) : (woT + wo);
  const bf16* Bt = isM ? (wqB + wo) : (wvB + wo);
  bf16* C = (isM ? Mt : Gt) + (size_t)zz * DIM * DIM;
  gemm_bt_body<2>(A, INNER, Bt, INNER, blockIdx.y * 64, 0, 0, DH, DIM, DIM,
                  isM ? QSCALE : 1.f, C, DIM);
}

// ---- per-row LayerNorm helper: one wave, row of 96 (v1 valid for lane<32) --
__device__ __forceinline__ void ln_row_vals(float v0, float v1in, int lane,
    const char* g, int f, float& o0, float& o1) {
  float v1 = (lane < 32) ? v1in : 0.f;
  float s = v0 + v1;
  #pragma unroll
  for (int off = 32; off > 0; off >>= 1) s += __shfl_xor(s, off);
  float mu = s * (1.f / 96.f);
  float d0 = v0 - mu;
  float d1 = (lane < 32) ? (v1 - mu) : 0.f;
  float q = d0 * d0 + d1 * d1;
  #pragma unroll
  for (int off = 32; off > 0; off >>= 1) q += __shfl_xor(q, off);
  float rstd = rsqrtf(q * (1.f / 96.f) + EPSLN);
  o0 = d0 * rstd * (gload(g, lane, f) + 1.f);
  o1 = (lane < 32) ? (d1 * rstd * (gload(g, 64 + lane, f) + 1.f)) : 0.f;
}

__device__ __forceinline__ void store_hn(bf16* hn, bf16* hnT, int row, int lane,
                                         float o0, float o1) {
  size_t base = (size_t)row * DIM;
  bf16* hT = hnT + (size_t)(row >> 9) * DIM * SEQ;
  int ss = row & (SEQ - 1);
  hn[base + lane] = f2b(o0);
  hT[(size_t)lane * SEQ + ss] = f2b(o0);
  if (lane < 32) {
    hn[base + 64 + lane] = f2b(o1);
    hT[(size_t)(64 + lane) * SEQ + ss] = f2b(o1);
  }
}

// ---- cast input + LN0 -> x, hn, hnT (grid 256 x 256t, 4 rows/block) --------
__global__ __launch_bounds__(256) void castln_kernel(
    const void* __restrict__ in_x, float* __restrict__ x,
    bf16* __restrict__ hn, bf16* __restrict__ hnT,
    const void* __restrict__ gb, const int* __restrict__ flagp) {
  int f = *flagp;
  int wave = threadIdx.x >> 6, lane = threadIdx.x & 63;
  int row = blockIdx.x * 4 + wave;
  size_t base = (size_t)row * DIM;
  float v0 = gload(in_x, base + lane, f);
  float v1 = (lane < 32) ? gload(in_x, base + 64 + lane, f) : 0.f;
  x[base + lane] = v0;
  if (lane < 32) x[base + 64 + lane] = v1;
  float o0, o1;
  ln_row_vals(v0, v1, lane, gptr(gb, 0, f), f, o0, o1);
  store_hn(hn, hnT, row, lane, o0, o1);
}

// ---- standalone LN (attn -> attn transition): grid 256 x 256t --------------
__global__ __launch_bounds__(256) void ln_kernel(
    const float* __restrict__ x, bf16* __restrict__ hn, bf16* __restrict__ hnT,
    const void* __restrict__ gb, size_t goff, const int* __restrict__ flagp) {
  int f = *flagp;
  int wave = threadIdx.x >> 6, lane = threadIdx.x & 63;
  int row = blockIdx.x * 4 + wave;
  size_t base = (size_t)row * DIM;
  float v0 = x[base + lane];
  float v1 = (lane < 32) ? x[base + 64 + lane] : 0.f;
  float o0, o1;
  ln_row_vals(v0, v1, lane, gptr(gb, goff, f), f, o0, o1);
  store_hn(hn, hnT, row, lane, o0, o1);
}

// ============== fused attention v4: 8 waves, halved critical path ===========
// grid (16 q-tiles, 16 z=b*8+h) x 512 threads.
// t + S + softmax + (P@hn)@Gt^T, B operands direct from L2-resident global.
__global__ __launch_bounds__(512) void fattn4_kernel(
    const bf16* __restrict__ hn,    // [1024][96]
    const bf16* __restrict__ hnT,   // [2][96][512]
    const bf16* __restrict__ MtL,   // [8][96][96]
    const bf16* __restrict__ GtL,   // [8][96][96]
    float* __restrict__ x) {
  __shared__ bf16 tP[32][520];
  __shared__ bf16 Zs[32][104];
  __shared__ float red[2][8][32];
  int tid = threadIdx.x, lane = tid & 63, wave = tid >> 6;  // wave 0..7
  int fm = lane & 15, fq = (lane >> 4) * 8;
  int col = lane & 15, rq = (lane >> 4) * 4;
  int z = blockIdx.y, b = z >> 3, h = z & 7;
  int m0 = blockIdx.x * 32;
  const bf16* hnB = hn + (size_t)b * SEQ * DIM;
  const bf16* hTB = hnT + (size_t)b * DIM * SEQ;
  const bf16* MtH = MtL + (size_t)h * DIM * DIM;
  const bf16* GtH = GtL + (size_t)h * DIM * DIM;

  // ---- stage 1: t = hn_tile[32x96] @ Mt^T; waves 0..5, 2 n-frags each ----
  if (wave < 6) {
    int mA = wave & 1, nb = wave >> 1;     // n-frags {nb, nb+3}
    f32x4 a0 = (f32x4){0.f, 0.f, 0.f, 0.f}, a1 = a0;
    #pragma unroll
    for (int kb = 0; kb < 96; kb += 32) {
      bf16x8 af = *(const bf16x8*)(hnB + (size_t)(m0 + mA * 16 + fm) * DIM + kb + fq);
      bf16x8 b0 = *(const bf16x8*)(MtH + (size_t)(nb * 16 + fm) * DIM + kb + fq);
      bf16x8 b1 = *(const bf16x8*)(MtH + (size_t)((nb + 3) * 16 + fm) * DIM + kb + fq);
      a0 = MFMA16(af, b0, a0);
      a1 = MFMA16(af, b1, a1);
    }
    #pragma unroll
    for (int r = 0; r < 4; r++) {
      Zs[mA * 16 + rq + r][nb * 16 + col] = f2b(a0[r]);
      Zs[mA * 16 + rq + r][(nb + 3) * 16 + col] = f2b(a1[r]);
    }
  }
  __syncthreads();

  // ---- stage 2: S = t @ hn^T (32 x 512); wave covers 64 cols ----
  f32x4 acc2[2][4];
  #pragma unroll
  for (int i = 0; i < 2; i++)
    #pragma unroll
    for (int j = 0; j < 4; j++) acc2[i][j] = (f32x4){0.f, 0.f, 0.f, 0.f};
  #pragma unroll
  for (int kb = 0; kb < 96; kb += 32) {
    bf16x8 af0 = *(const bf16x8*)&Zs[fm][kb + fq];
    bf16x8 af1 = *(const bf16x8*)&Zs[16 + fm][kb + fq];
    bf16x8 bv[4];
    #pragma unroll
    for (int j = 0; j < 4; j++)
      bv[j] = *(const bf16x8*)(hnB + (size_t)(wave * 64 + j * 16 + fm) * DIM + kb + fq);
    #pragma unroll
    for (int j = 0; j < 4; j++) {
      acc2[0][j] = MFMA16(af0, bv[j], acc2[0][j]);
      acc2[1][j] = MFMA16(af1, bv[j], acc2[1][j]);
    }
  }

  // ---- softmax over 512 cols (8 wave-partials) ----
  float rmax[2][4];
  #pragma unroll
  for (int i = 0; i < 2; i++)
    #pragma unroll
    for (int r = 0; r < 4; r++) {
      float m = -1e30f;
      #pragma unroll
      for (int j = 0; j < 4; j++) m = fmaxf(m, acc2[i][j][r]);
      rmax[i][r] = m;
    }
  #pragma unroll
  for (int s = 1; s < 16; s <<= 1)
    #pragma unroll
    for (int i = 0; i < 2; i++)
      #pragma unroll
      for (int r = 0; r < 4; r++)
        rmax[i][r] = fmaxf(rmax[i][r], __shfl_xor(rmax[i][r], s));
  if (col == 0)
    #pragma unroll
    for (int i = 0; i < 2; i++)
      #pragma unroll
      for (int r = 0; r < 4; r++) red[0][wave][i * 16 + rq + r] = rmax[i][r];
  __syncthreads();
  float rsum[2][4];
  #pragma unroll
  for (int i = 0; i < 2; i++)
    #pragma unroll
    for (int r = 0; r < 4; r++) {
      int row = i * 16 + rq + r;
      float gm = red[0][0][row];
      #pragma unroll
      for (int q = 1; q < 8; q++) gm = fmaxf(gm, red[0][q][row]);
      float s = 0.f;
      #pragma unroll
      for (int j = 0; j < 4; j++) {
        float e = __expf(acc2[i][j][r] - gm);
        acc2[i][j][r] = e;
        s += e;
      }
      rsum[i][r] = s;
    }
  #pragma unroll
  for (int s = 1; s < 16; s <<= 1)
    #pragma unroll
    for (int i = 0; i < 2; i++)
      #pragma unroll
      for (int r = 0; r < 4; r++)
        rsum[i][r] += __shfl_xor(rsum[i][r], s);
  if (col == 0)
    #pragma unroll
    for (int i = 0; i < 2; i++)
      #pragma unroll
      for (int r = 0; r < 4; r++) red[1][wave][i * 16 + rq + r] = rsum[i][r];
  __syncthreads();

  // each wave writes its own normalized 64-col P chunk
  #pragma unroll
  for (int i = 0; i < 2; i++)
    #pragma unroll
    for (int r = 0; r < 4; r++) {
      int row = i * 16 + rq + r;
      float tot = red[1][0][row];
      #pragma unroll
      for (int q = 1; q < 8; q++) tot += red[1][q][row];
      float inv = 1.f / tot;
      #pragma unroll
      for (int j = 0; j < 4; j++)
        tP[row][wave * 64 + j * 16 + col] = f2b(acc2[i][j][r] * inv);
    }
  __syncthreads();

  // ---- stage 3a: Z = P @ hnT^T (32 x 96), K = 512 ----
  // waves 0..3: both m-frags of n=wave; waves 4..7: one frag (m=w&1, n=(w>>1)+2)
  f32x4 z0 = (f32x4){0.f, 0.f, 0.f, 0.f}, z1 = z0;
  if (wave < 4) {
    int n = wave;
    #pragma unroll 4
    for (int kb = 0; kb < 512; kb += 32) {
      bf16x8 bv = *(const bf16x8*)(hTB + (size_t)(n * 16 + fm) * SEQ + kb + fq);
      bf16x8 af0 = *(const bf16x8*)&tP[fm][kb + fq];
      bf16x8 af1 = *(const bf16x8*)&tP[16 + fm][kb + fq];
      z0 = MFMA16(af0, bv, z0);
      z1 = MFMA16(af1, bv, z1);
    }
    #pragma unroll
    for (int r = 0; r < 4; r++) {
      Zs[rq + r][n * 16 + col] = f2b(z0[r]);
      Zs[16 + rq + r][n * 16 + col] = f2b(z1[r]);
    }
  } else {
    int mA = wave & 1, n = (wave >> 1) + 2;   // wave 4,5 -> n=4; 6,7 -> n=5
    #pragma unroll 4
    for (int kb = 0; kb < 512; kb += 32) {
      bf16x8 bv = *(const bf16x8*)(hTB + (size_t)(n * 16 + fm) * SEQ + kb + fq);
      bf16x8 af = *(const bf16x8*)&tP[mA * 16 + fm][kb + fq];
      z0 = MFMA16(af, bv, z0);
    }
    #pragma unroll
    for (int r = 0; r < 4; r++)
      Zs[mA * 16 + rq + r][n * 16 + col] = f2b(z0[r]);
  }
  __syncthreads();

  // ---- stage 3b: O = Z @ Gt^T (32 x 96); waves 0..5, 2 n-frags each ----
  if (wave < 6) {
    int mA = wave & 1, nb = wave >> 1;
    f32x4 o0 = (f32x4){0.f, 0.f, 0.f, 0.f}, o1 = o0;
    #pragma unroll
    for (int kb = 0; kb < 96; kb += 32) {
      bf16x8 af = *(const bf16x8*)&Zs[mA * 16 + fm][kb + fq];
      bf16x8 b0 = *(const bf16x8*)(GtH + (size_t)(nb * 16 + fm) * DIM + kb + fq);
      bf16x8 b1 = *(const bf16x8*)(GtH + (size_t)((nb + 3) * 16 + fm) * DIM + kb + fq);
      o0 = MFMA16(af, b0, o0);
      o1 = MFMA16(af, b1, o1);
    }
    #pragma unroll
    for (int r = 0; r < 4; r++) {
      int gr = b * SEQ + m0 + mA * 16 + rq + r;
      atomicAdd(x + (size_t)gr * DIM + nb * 16 + col, o0[r]);
      atomicAdd(x + (size_t)gr * DIM + (nb + 3) * 16 + col, o1[r]);
    }
  }
}

// ====== fused MLP (8 waves): [gmid-LN] + LN + GEMM1 + GELU + GEMM2 + res ====
// grid (32) x 512 threads; each block owns 32 rows. LN epilogue:
// lnmode 1 -> hn/hnT with gamma(lngb+lngoff); lnmode 2 -> final LN to dout.
__global__ __launch_bounds__(512) void fmlp_kernel(
    float* __restrict__ X,
    const void* __restrict__ gmidb, size_t gmidoff, int useMid,
    const void* __restrict__ gmb, size_t gmoff,
    const bf16* __restrict__ w1T,   // [384][96]
    const void* __restrict__ b1b, size_t b1off,
    const bf16* __restrict__ w2T,   // [96][384]
    const void* __restrict__ b2b, size_t b2off,
    int lnmode, const void* __restrict__ lngb, size_t lngoff,
    bf16* __restrict__ hn, bf16* __restrict__ hnT, void* __restrict__ dout,
    const int* __restrict__ flagp) {
  __shared__ float X1s[32][96];
  __shared__ bf16 As[32][104];
  __shared__ bf16 Hs[32][392];
  int f = *flagp;
  int tid = threadIdx.x, lane = tid & 63, wave = tid >> 6;  // 0..7
  int fm = lane & 15, fq = (lane >> 4) * 8;
  int col = lane & 15, rq = (lane >> 4) * 4;
  int m0 = blockIdx.x * 32;
  const char* gm = gptr(gmb, gmoff, f);
  float gm0 = gload(gm, lane, f) + 1.f;
  float gm1 = (lane < 32) ? (gload(gm, 64 + lane, f) + 1.f) : 0.f;
  float gd0 = 1.f, gd1 = 1.f;
  if (useMid) {
    const char* gmid = gptr(gmidb, gmidoff, f);
    gd0 = gload(gmid, lane, f) + 1.f;
    gd1 = (lane < 32) ? (gload(gmid, 64 + lane, f) + 1.f) : 0.f;
  }
  for (int r = wave; r < 32; r += 8) {
    const float* xr = X + (size_t)(m0 + r) * DIM;
    float v0 = xr[lane];
    float v1 = (lane < 32) ? xr[64 + lane] : 0.f;
    if (useMid) {
      float s = v0 + v1;
      #pragma unroll
      for (int off = 32; off > 0; off >>= 1) s += __shfl_xor(s, off);
      float mu = s * (1.f / 96.f);
      float d0 = v0 - mu;
      float d1 = (lane < 32) ? (v1 - mu) : 0.f;
      float q = d0 * d0 + d1 * d1;
      #pragma unroll
      for (int off = 32; off > 0; off >>= 1) q += __shfl_xor(q, off);
      float rstd = rsqrtf(q * (1.f / 96.f) + EPSLN);
      v0 = d0 * rstd * gd0;
      v1 = (lane < 32) ? (d1 * rstd * gd1) : 0.f;
    }
    X1s[r][lane] = v0;
    if (lane < 32) X1s[r][64 + lane] = v1;
    float s = v0 + v1;
    #pragma unroll
    for (int off = 32; off > 0; off >>= 1) s += __shfl_xor(s, off);
    float mu = s * (1.f / 96.f);
    float d0 = v0 - mu;
    float d1 = (lane < 32) ? (v1 - mu) : 0.f;
    float q = d0 * d0 + d1 * d1;
    #pragma unroll
    for (int off = 32; off > 0; off >>= 1) q += __shfl_xor(q, off);
    float rstd = rsqrtf(q * (1.f / 96.f) + EPSLN);
    As[r][lane] = f2b(d0 * rstd * gm0);
    if (lane < 32) As[r][64 + lane] = f2b(d1 * rstd * gm1);
  }
  __syncthreads();

  // ---- GEMM1: [32x96] @ W1 -> [32x384]; wave = (m, 96-col chunk) ----
  int mw = wave & 1, nh = wave >> 1;     // nh in 0..3: cols [nh*96, nh*96+96)
  f32x4 acc1[6];
  #pragma unroll
  for (int j = 0; j < 6; j++) acc1[j] = (f32x4){0.f, 0.f, 0.f, 0.f};
  #pragma unroll
  for (int kb = 0; kb < 96; kb += 32) {
    bf16x8 af = *(const bf16x8*)&As[mw * 16 + fm][kb + fq];
    #pragma unroll
    for (int j = 0; j < 6; j++) {
      bf16x8 bv = *(const bf16x8*)(w1T + (size_t)(nh * 96 + j * 16 + fm) * DIM + kb + fq);
      acc1[j] = MFMA16(af, bv, acc1[j]);
    }
  }
  const char* b1p = gptr(b1b, b1off, f);
  #pragma unroll
  for (int j = 0; j < 6; j++) {
    int gn = nh * 96 + j * 16 + col;
    float bv = gload(b1p, gn, f);
    #pragma unroll
    for (int r = 0; r < 4; r++) {
      float v = acc1[j][r] + bv;
      v = 0.5f * v * (1.f + erff(v * 0.70710678118f));
      Hs[mw * 16 + rq + r][gn] = f2b(v);
    }
  }
  __syncthreads();

  // ---- GEMM2: [32x384] @ W2 -> [32x96]; waves 0..5, 2 n-frags each ----
  if (wave < 6) {
    int mA = wave & 1, nb = wave >> 1;
    f32x4 o0 = (f32x4){0.f, 0.f, 0.f, 0.f}, o1 = o0;
    #pragma unroll 4
    for (int kb = 0; kb < 384; kb += 32) {
      bf16x8 af = *(const bf16x8*)&Hs[mA * 16 + fm][kb + fq];
      bf16x8 b0 = *(const bf16x8*)(w2T + (size_t)(nb * 16 + fm) * HIDN + kb + fq);
      bf16x8 b1 = *(const bf16x8*)(w2T + (size_t)((nb + 3) * 16 + fm) * HIDN + kb + fq);
      o0 = MFMA16(af, b0, o0);
      o1 = MFMA16(af, b1, o1);
    }
    const char* b2p = gptr(b2b, b2off, f);
    float bb0 = gload(b2p, nb * 16 + col, f);
    float bb1 = gload(b2p, (nb + 3) * 16 + col, f);
    #pragma unroll
    for (int r = 0; r < 4; r++) {
      int row = mA * 16 + rq + r;
      int gmr = m0 + row;
      X[(size_t)gmr * DIM + nb * 16 + col] = X1s[row][nb * 16 + col] + o0[r] + bb0;
      X[(size_t)gmr * DIM + (nb + 3) * 16 + col] = X1s[row][(nb + 3) * 16 + col] + o1[r] + bb1;
    }
  }
  __syncthreads();

  // ---- fused LN epilogue over this block's 32 rows ----
  const char* lg = gptr(lngb, lngoff, f);
  for (int r = wave; r < 32; r += 8) {
    int row = m0 + r;
    size_t base = (size_t)row * DIM;
    float v0 = X[base + lane];
    float v1 = (lane < 32) ? X[base + 64 + lane] : 0.f;
    float o0, o1;
    ln_row_vals(v0, v1, lane, lg, f, o0, o1);
    if (lnmode == 1) {
      store_hn(hn, hnT, row, lane, o0, o1);
    } else {
      if (!f) {
        ((float*)dout)[base + lane] = o0;
        if (lane < 32) ((float*)dout)[base + 64 + lane] = o1;
      } else {
        ((bf16*)dout)[base + lane] = f2b(o0);
        if (lane < 32) ((bf16*)dout)[base + 64 + lane] = f2b(o1);
      }
    }
  }
}

// ---------------- host-side orchestration ----------------
extern "C" void kernel_launch(void* const* d_in, const int* in_sizes, int n_in,
                              void* d_out, int out_size, void* d_ws, size_t ws_size,
                              hipStream_t stream) {
  const void* in_x    = d_in[0];
  const void* gam_a   = d_in[1];
  const void* Wq      = d_in[2];
  const void* Wk      = d_in[3];
  const void* Wv      = d_in[4];
  const void* Wo      = d_in[5];
  const void* gam_m   = d_in[6];
  const void* W1      = d_in[7];
  const void* b1      = d_in[8];
  const void* W2      = d_in[9];
  const void* b2      = d_in[10];
  const void* gam_mid = d_in[11];
  const void* gam_fin = d_in[12];

  char* wsb = (char*)d_ws;
  size_t off = 0;
  auto carve = [&](size_t bytes) {
    char* p = wsb + off;
    off += (bytes + 255) & ~(size_t)255;
    return p;
  };
  int*   flag = (int*)carve(256);
  float* x    = (float*)carve((size_t)TOK * DIM * 4);
  bf16*  hn   = (bf16*)carve((size_t)TOK * DIM * 2);
  bf16*  hnT  = (bf16*)carve((size_t)2 * DIM * SEQ * 2);
  const size_t WSZ = (size_t)15 * DIM * INNER;   // per big weight, elements
  bf16*  wqB  = (bf16*)carve(WSZ * 2);
  bf16*  wkB  = (bf16*)carve(WSZ * 2);
  bf16*  wvB  = (bf16*)carve(WSZ * 2);
  bf16*  woT  = (bf16*)carve(WSZ * 2);
  bf16*  w1T  = (bf16*)carve((size_t)10 * DIM * HIDN * 2);
  bf16*  w2T  = (bf16*)carve((size_t)10 * DIM * HIDN * 2);
  bf16*  Mt   = (bf16*)carve((size_t)120 * DIM * DIM * 2);
  bf16*  Gt   = (bf16*)carve((size_t)120 * DIM * DIM * 2);

  detect_kernel<<<dim3(1), dim3(256), 0, stream>>>(in_x, flag);

  // ---- once-per-call weight prep ----
  int nW = (int)WSZ;
  castw3_kernel<<<dim3((nW / 4 + 255) / 256, 3), dim3(256), 0, stream>>>(
      Wq, Wk, Wv, wqB, wkB, wvB, nW, flag);
  wtrans_kernel<<<dim3(3, 192, 15), dim3(256), 0, stream>>>(Wo, INNER, DIM, woT, flag);
  wtrans_kernel<<<dim3(12, 3, 10), dim3(256), 0, stream>>>(W1, DIM, HIDN, w1T, flag);
  wtrans_kernel<<<dim3(3, 12, 10), dim3(256), 0, stream>>>(W2, HIDN, DIM, w2T, flag);
  mtgt_kernel<<<dim3(1, 2, 240), dim3(256), 0, stream>>>(wqB, wkB, wvB, woT, Mt, Gt);

  // stage 0: cast input + LN(gam_a[0,0]) -> x, hn, hnT
  castln_kernel<<<dim3(TOK / 4), dim3(256), 0, stream>>>(in_x, x, hn, hnT, gam_a, flag);

  auto attn = [&](int d, int j) {
    size_t gi = ((size_t)d * 3 + j);
    fattn4_kernel<<<dim3(16, 16), dim3(512), 0, stream>>>(
        hn, hnT, Mt + gi * 8 * DIM * DIM, Gt + gi * 8 * DIM * DIM, x);
  };

  for (int d = 0; d < NDEPTH; d++) {
    bool last = (d == NDEPTH - 1);
    attn(d, 0);
    // mlp0 + fused LN(gam_a[d,1]) -> hn/hnT for attn1
    fmlp_kernel<<<dim3(32), dim3(512), 0, stream>>>(
        x, nullptr, 0, 0,
        gam_m, (size_t)(d * 2 + 0) * DIM,
        w1T + (size_t)(d * 2 + 0) * DIM * HIDN, b1, (size_t)(d * 2 + 0) * HIDN,
        w2T + (size_t)(d * 2 + 0) * DIM * HIDN, b2, (size_t)(d * 2 + 0) * DIM,
        1, gam_a, (size_t)(d * 3 + 1) * DIM, hn, hnT, nullptr, flag);
    attn(d, 1);
    ln_kernel<<<dim3(TOK / 4), dim3(256), 0, stream>>>(
        x, hn, hnT, gam_a, (size_t)(d * 3 + 2) * DIM, flag);
    attn(d, 2);
    // mlp1 (includes bare mid-LN) + fused LN: next gam_a[.,0] or final -> dout
    fmlp_kernel<<<dim3(32), dim3(512), 0, stream>>>(
        x, gam_mid, (size_t)d * DIM, 1,
        gam_m, (size_t)(d * 2 + 1) * DIM,
        w1T + (size_t)(d * 2 + 1) * DIM * HIDN, b1, (size_t)(d * 2 + 1) * HIDN,
        w2T + (size_t)(d * 2 + 1) * DIM * HIDN, b2, (size_t)(d * 2 + 1) * DIM,
        last ? 2 : 1, last ? gam_fin : gam_a,
        last ? (size_t)0 : (size_t)((d + 1) * 3) * DIM,
        hn, hnT, d_out, flag);
  }
}

// Round 5
// 682.623 us; speedup vs baseline: 2.0845x; 1.0301x over previous
//
#include <hip/hip_runtime.h>
#include <hip/hip_bf16.h>

typedef __hip_bfloat16 bf16;
typedef __attribute__((ext_vector_type(8))) short bf16x8;   // 8 bf16 = 4 VGPRs
typedef __attribute__((ext_vector_type(4))) float f32x4;

#define TOK    1024
#define DIM    96
#define HIDN   384
#define HEADS  8
#define DH     768
#define INNER  6144
#define SEQ    512
#define NDEPTH 5
#define EPSLN  1e-5f
#define QSCALE 0.125f

#define MFMA16(a, b, c) __builtin_amdgcn_mfma_f32_16x16x32_bf16((a), (b), (c), 0, 0, 0)

__device__ __forceinline__ float b2f(bf16 v) { return __bfloat162float(v); }
__device__ __forceinline__ bf16  f2b(float v) { return __float2bfloat16(v); }

// Load element i from an external input buffer: f==1 -> bf16, f==0 -> fp32.
__device__ __forceinline__ float gload(const void* p, size_t i, int f) {
  return f ? b2f(((const bf16*)p)[i]) : ((const float*)p)[i];
}
__device__ __forceinline__ const char* gptr(const void* base, size_t off, int f) {
  return (const char*)base + off * (size_t)(f ? 2 : 4);
}

// ---------------- dtype detector (bf16 vs fp32 external buffers) ------------
__global__ __launch_bounds__(256) void detect_kernel(const void* xraw, int* flag) {
  __shared__ int cnt[256];
  int t = threadIdx.x;
  const unsigned short* u = (const unsigned short*)xraw;
  int c = 0;
  #pragma unroll
  for (int i = 0; i < 4; i++) {
    unsigned short h = u[2 * (t * 4 + i)];
    int e = (h >> 7) & 0xFF;
    if (e >= 87 && e <= 132) c++;
  }
  cnt[t] = c;
  __syncthreads();
  for (int s = 128; s > 0; s >>= 1) {
    if (t < s) cnt[t] += cnt[t + s];
    __syncthreads();
  }
  if (t == 0) *flag = (cnt[0] > 700) ? 1 : 0;
}

// ------- cast 3 external weights -> bf16 copies. Only needed for fp32 -------
// (f==1: external buffers are already bf16 with identical layout; mtgt reads
//  them directly and this kernel early-outs.)
__global__ __launch_bounds__(256) void castw3_kernel(
    const void* __restrict__ w0, const void* __restrict__ w1,
    const void* __restrict__ w2, bf16* __restrict__ o0,
    bf16* __restrict__ o1, bf16* __restrict__ o2, int n,
    const int* __restrict__ flagp) {
  if (*flagp) return;   // bf16 inputs: no copy needed
  const float* in = (const float*)((blockIdx.y == 0) ? w0 : (blockIdx.y == 1) ? w1 : w2);
  bf16* out = (blockIdx.y == 0) ? o0 : (blockIdx.y == 1) ? o1 : o2;
  int i0 = (blockIdx.x * blockDim.x + threadIdx.x) * 4;
  if (i0 + 3 < n) {
    float4 v = *(const float4*)(in + i0);
    alignas(8) unsigned short o[4];
    bf16 t0 = f2b(v.x); o[0] = *(unsigned short*)&t0;
    bf16 t1 = f2b(v.y); o[1] = *(unsigned short*)&t1;
    bf16 t2 = f2b(v.z); o[2] = *(unsigned short*)&t2;
    bf16 t3 = f2b(v.w); o[3] = *(unsigned short*)&t3;
    *(uint2*)&out[i0] = *(const uint2*)o;
  } else {
    for (int i = i0; i < n; i++) out[i] = f2b(in[i]);
  }
}

// -------- weight transpose+convert: [bz][R][C] -> bf16 [bz][C][R] -----------
// Vectorized: 8B bf16 / 16B fp32 loads, 16B stores. Requires R%32==0, C%4==0
// (true for Wo 6144x96, W1 96x384, W2 384x96). Grid (ceil(C/64), R/32, bz).
__global__ __launch_bounds__(256) void wtrans_kernel(
    const void* __restrict__ src, int R, int C,
    bf16* __restrict__ dst, const int* __restrict__ flagp) {
  __shared__ float tile[32][65];
  int f = *flagp;
  int t = threadIdx.x;
  int c0 = blockIdx.x * 64, r0 = blockIdx.y * 32;
  size_t bb = (size_t)blockIdx.z * R * C;
  // ---- load 32 rows x 64 cols; thread: rows ty, ty+16; cols tx*4..tx*4+3 ---
  int ty = t >> 4, tx = t & 15;
  #pragma unroll
  for (int half = 0; half < 2; half++) {
    int r = r0 + ty + half * 16;
    int c = c0 + tx * 4;
    if (c < C) {   // C%4==0 -> 4-group fully in or fully out
      size_t idx = bb + (size_t)r * C + c;
      float v0, v1, v2, v3;
      if (f) {
        uint2 u = *(const uint2*)((const unsigned short*)src + idx);
        v0 = __uint_as_float((u.x & 0xffffu) << 16);
        v1 = __uint_as_float(u.x & 0xffff0000u);
        v2 = __uint_as_float((u.y & 0xffffu) << 16);
        v3 = __uint_as_float(u.y & 0xffff0000u);
      } else {
        float4 v = *(const float4*)((const float*)src + idx);
        v0 = v.x; v1 = v.y; v2 = v.z; v3 = v.w;
      }
      tile[ty + half * 16][tx * 4 + 0] = v0;
      tile[ty + half * 16][tx * 4 + 1] = v1;
      tile[ty + half * 16][tx * 4 + 2] = v2;
      tile[ty + half * 16][tx * 4 + 3] = v3;
    }
  }
  __syncthreads();
  // ---- store transposed: thread: col cc = c0 + (t>>2), rows rseg..rseg+7 ---
  int cc = c0 + (t >> 2), rseg = (t & 3) * 8;
  if (cc < C) {
    int cs = cc - c0;
    alignas(16) unsigned short o[8];
    #pragma unroll
    for (int j = 0; j < 8; j++) {
      bf16 tv = f2b(tile[rseg + j][cs]);
      o[j] = *(unsigned short*)&tv;
    }
    *(uint4*)&dst[bb + (size_t)cc * R + r0 + rseg] = *(const uint4*)o;
  }
}

// =================== MFMA GEMM body — BT form (B is bf16 [N][K]) ============
// Used only by mtgt (weight-folding prep). Block 256 = 4 waves (2x2).
template <int WM>
__device__ __forceinline__ void gemm_bt_body(
    const bf16* __restrict__ A, int lda,
    const bf16* __restrict__ Bt, int ldb,
    int m0, int n0, int kbeg, int kend, int Mtot, int N,
    float alpha, bf16* __restrict__ Cb, int ldc) {
  constexpr int TM = WM * 32;
  __shared__ bf16 As[TM][40];
  __shared__ bf16 Bs[128][40];
  int t = threadIdx.x;
  int lane = t & 63;
  int wave = t >> 6;
  int wm = (wave >> 1) * (WM * 16), wn = (wave & 1) * 64;
  f32x4 acc[WM][4];
  #pragma unroll
  for (int i = 0; i < WM; i++)
    #pragma unroll
    for (int j = 0; j < 4; j++) acc[i][j] = (f32x4){0.f, 0.f, 0.f, 0.f};

  int arow = t >> 2, aseg = (t & 3) * 8;

  for (int kb = kbeg; kb < kend; kb += 32) {
    if constexpr (TM >= 64) {
      #pragma unroll
      for (int i = 0; i < TM / 64; i++) {
        int gm = min(m0 + arow + i * 64, Mtot - 1);
        *(uint4*)&As[arow + i * 64][aseg] =
            *(const uint4*)(A + (size_t)gm * lda + kb + aseg);
      }
    } else {
      if (arow < TM) {
        int gm = min(m0 + arow, Mtot - 1);
        *(uint4*)&As[arow][aseg] =
            *(const uint4*)(A + (size_t)gm * lda + kb + aseg);
      }
    }
    #pragma unroll
    for (int i = 0; i < 2; i++) {
      int r = arow + i * 64;
      int gn = n0 + r;
      uint4 val = {0, 0, 0, 0};
      if (gn < N) val = *(const uint4*)(Bt + (size_t)gn * ldb + kb + aseg);
      *(uint4*)&Bs[r][aseg] = val;
    }
    __syncthreads();
    int fm = lane & 15, fq = (lane >> 4) * 8;
    bf16x8 af[WM], bfv[4];
    #pragma unroll
    for (int i = 0; i < WM; i++)
      af[i] = *(const bf16x8*)&As[wm + i * 16 + fm][fq];
    #pragma unroll
    for (int j = 0; j < 4; j++)
      bfv[j] = *(const bf16x8*)&Bs[wn + j * 16 + fm][fq];
    #pragma unroll
    for (int i = 0; i < WM; i++)
      #pragma unroll
      for (int j = 0; j < 4; j++)
        acc[i][j] = MFMA16(af[i], bfv[j], acc[i][j]);
    __syncthreads();
  }
  int col = lane & 15, rq = (lane >> 4) * 4;
  #pragma unroll
  for (int j = 0; j < 4; j++) {
    int gn = n0 + wn + j * 16 + col;
    if (gn >= N) continue;
    #pragma unroll
    for (int i = 0; i < WM; i++) {
      #pragma unroll
      for (int r = 0; r < 4; r++) {
        int gm = m0 + wm + i * 16 + rq + r;
        if (gm >= Mtot) continue;
        Cb[(size_t)gm * ldc + gn] = f2b(acc[i][j][r] * alpha);
      }
    }
  }
}

// ---- precompute Mt (z<120) and Gt (z>=120): grid (1, 2, 240) ---------------
// f==1: read external bf16 Wq/Wk/Wv directly (identical layout); else copies.
__global__ __launch_bounds__(256) void mtgt_kernel(
    const void* __restrict__ WqE, const void* __restrict__ WkE,
    const void* __restrict__ WvE,
    const bf16* __restrict__ wqB, const bf16* __restrict__ wkB,
    const bf16* __restrict__ wvB, const bf16* __restrict__ woT,
    bf16* __restrict__ Mt, bf16* __restrict__ Gt,
    const int* __restrict__ flagp) {
  int f = *flagp;
  const bf16* wq = f ? (const bf16*)WqE : wqB;
  const bf16* wk = f ? (const bf16*)WkE : wkB;
  const bf16* wv = f ? (const bf16*)WvE : wvB;
  int z = blockIdx.z;
  bool isM = z < 120;
  int zz = isM ? z : z - 120;
  int L = zz >> 3, h = zz & 7;
  size_t wo = (size_t)L * DIM * INNER + (size_t)h * DH;
  const bf16* A  = isM ? (wk + wo) : (woT + wo);
  const bf16* Bt = isM ? (wq + wo) : (wv + wo);
  bf16* C = (isM ? Mt : Gt) + (size_t)zz * DIM * DIM;
  gemm_bt_body<2>(A, INNER, Bt, INNER, blockIdx.y * 64, 0, 0, DH, DIM, DIM,
                  isM ? QSCALE : 1.f, C, DIM);
}

// ---- per-row LayerNorm helper: one wave, row of 96 (v1 valid for lane<32) --
__device__ __forceinline__ void ln_row_vals(float v0, float v1in, int lane,
    const char* g, int f, float& o0, float& o1) {
  float v1 = (lane < 32) ? v1in : 0.f;
  float s = v0 + v1;
  #pragma unroll
  for (int off = 32; off > 0; off >>= 1) s += __shfl_xor(s, off);
  float mu = s * (1.f / 96.f);
  float d0 = v0 - mu;
  float d1 = (lane < 32) ? (v1 - mu) : 0.f;
  float q = d0 * d0 + d1 * d1;
  #pragma unroll
  for (int off = 32; off > 0; off >>= 1) q += __shfl_xor(q, off);
  float rstd = rsqrtf(q * (1.f / 96.f) + EPSLN);
  o0 = d0 * rstd * (gload(g, lane, f) + 1.f);
  o1 = (lane < 32) ? (d1 * rstd * (gload(g, 64 + lane, f) + 1.f)) : 0.f;
}

__device__ __forceinline__ void store_hn(bf16* hn, bf16* hnT, int row, int lane,
                                         float o0, float o1) {
  size_t base = (size_t)row * DIM;
  bf16* hT = hnT + (size_t)(row >> 9) * DIM * SEQ;
  int ss = row & (SEQ - 1);
  hn[base + lane] = f2b(o0);
  hT[(size_t)lane * SEQ + ss] = f2b(o0);
  if (lane < 32) {
    hn[base + 64 + lane] = f2b(o1);
    hT[(size_t)(64 + lane) * SEQ + ss] = f2b(o1);
  }
}

// ---- cast input + LN0 -> x, hn, hnT (grid 256 x 256t, 4 rows/block) --------
__global__ __launch_bounds__(256) void castln_kernel(
    const void* __restrict__ in_x, float* __restrict__ x,
    bf16* __restrict__ hn, bf16* __restrict__ hnT,
    const void* __restrict__ gb, const int* __restrict__ flagp) {
  int f = *flagp;
  int wave = threadIdx.x >> 6, lane = threadIdx.x & 63;
  int row = blockIdx.x * 4 + wave;
  size_t base = (size_t)row * DIM;
  float v0 = gload(in_x, base + lane, f);
  float v1 = (lane < 32) ? gload(in_x, base + 64 + lane, f) : 0.f;
  x[base + lane] = v0;
  if (lane < 32) x[base + 64 + lane] = v1;
  float o0, o1;
  ln_row_vals(v0, v1, lane, gptr(gb, 0, f), f, o0, o1);
  store_hn(hn, hnT, row, lane, o0, o1);
}

// ---- standalone LN (attn -> attn transition): grid 256 x 256t --------------
__global__ __launch_bounds__(256) void ln_kernel(
    const float* __restrict__ x, bf16* __restrict__ hn, bf16* __restrict__ hnT,
    const void* __restrict__ gb, size_t goff, const int* __restrict__ flagp) {
  int f = *flagp;
  int wave = threadIdx.x >> 6, lane = threadIdx.x & 63;
  int row = blockIdx.x * 4 + wave;
  size_t base = (size_t)row * DIM;
  float v0 = x[base + lane];
  float v1 = (lane < 32) ? x[base + 64 + lane] : 0.f;
  float o0, o1;
  ln_row_vals(v0, v1, lane, gptr(gb, goff, f), f, o0, o1);
  store_hn(hn, hnT, row, lane, o0, o1);
}

// ============== fused attention v4: 8 waves, halved critical path ===========
// grid (16 q-tiles, 16 z=b*8+h) x 512 threads.
// t + S + softmax + (P@hn)@Gt^T, B operands direct from L2-resident global.
__global__ __launch_bounds__(512) void fattn4_kernel(
    const bf16* __restrict__ hn,    // [1024][96]
    const bf16* __restrict__ hnT,   // [2][96][512]
    const bf16* __restrict__ MtL,   // [8][96][96]
    const bf16* __restrict__ GtL,   // [8][96][96]
    float* __restrict__ x) {
  __shared__ bf16 tP[32][520];
  __shared__ bf16 Zs[32][104];
  __shared__ float red[2][8][32];
  int tid = threadIdx.x, lane = tid & 63, wave = tid >> 6;  // wave 0..7
  int fm = lane & 15, fq = (lane >> 4) * 8;
  int col = lane & 15, rq = (lane >> 4) * 4;
  int z = blockIdx.y, b = z >> 3, h = z & 7;
  int m0 = blockIdx.x * 32;
  const bf16* hnB = hn + (size_t)b * SEQ * DIM;
  const bf16* hTB = hnT + (size_t)b * DIM * SEQ;
  const bf16* MtH = MtL + (size_t)h * DIM * DIM;
  const bf16* GtH = GtL + (size_t)h * DIM * DIM;

  // ---- stage 1: t = hn_tile[32x96] @ Mt^T; waves 0..5, 2 n-frags each ----
  if (wave < 6) {
    int mA = wave & 1, nb = wave >> 1;     // n-frags {nb, nb+3}
    f32x4 a0 = (f32x4){0.f, 0.f, 0.f, 0.f}, a1 = a0;
    #pragma unroll
    for (int kb = 0; kb < 96; kb += 32) {
      bf16x8 af = *(const bf16x8*)(hnB + (size_t)(m0 + mA * 16 + fm) * DIM + kb + fq);
      bf16x8 b0 = *(const bf16x8*)(MtH + (size_t)(nb * 16 + fm) * DIM + kb + fq);
      bf16x8 b1 = *(const bf16x8*)(MtH + (size_t)((nb + 3) * 16 + fm) * DIM + kb + fq);
      a0 = MFMA16(af, b0, a0);
      a1 = MFMA16(af, b1, a1);
    }
    #pragma unroll
    for (int r = 0; r < 4; r++) {
      Zs[mA * 16 + rq + r][nb * 16 + col] = f2b(a0[r]);
      Zs[mA * 16 + rq + r][(nb + 3) * 16 + col] = f2b(a1[r]);
    }
  }
  __syncthreads();

  // ---- stage 2: S = t @ hn^T (32 x 512); wave covers 64 cols ----
  f32x4 acc2[2][4];
  #pragma unroll
  for (int i = 0; i < 2; i++)
    #pragma unroll
    for (int j = 0; j < 4; j++) acc2[i][j] = (f32x4){0.f, 0.f, 0.f, 0.f};
  #pragma unroll
  for (int kb = 0; kb < 96; kb += 32) {
    bf16x8 af0 = *(const bf16x8*)&Zs[fm][kb + fq];
    bf16x8 af1 = *(const bf16x8*)&Zs[16 + fm][kb + fq];
    bf16x8 bv[4];
    #pragma unroll
    for (int j = 0; j < 4; j++)
      bv[j] = *(const bf16x8*)(hnB + (size_t)(wave * 64 + j * 16 + fm) * DIM + kb + fq);
    #pragma unroll
    for (int j = 0; j < 4; j++) {
      acc2[0][j] = MFMA16(af0, bv[j], acc2[0][j]);
      acc2[1][j] = MFMA16(af1, bv[j], acc2[1][j]);
    }
  }

  // ---- softmax over 512 cols (8 wave-partials) ----
  float rmax[2][4];
  #pragma unroll
  for (int i = 0; i < 2; i++)
    #pragma unroll
    for (int r = 0; r < 4; r++) {
      float m = -1e30f;
      #pragma unroll
      for (int j = 0; j < 4; j++) m = fmaxf(m, acc2[i][j][r]);
      rmax[i][r] = m;
    }
  #pragma unroll
  for (int s = 1; s < 16; s <<= 1)
    #pragma unroll
    for (int i = 0; i < 2; i++)
      #pragma unroll
      for (int r = 0; r < 4; r++)
        rmax[i][r] = fmaxf(rmax[i][r], __shfl_xor(rmax[i][r], s));
  if (col == 0)
    #pragma unroll
    for (int i = 0; i < 2; i++)
      #pragma unroll
      for (int r = 0; r < 4; r++) red[0][wave][i * 16 + rq + r] = rmax[i][r];
  __syncthreads();
  float rsum[2][4];
  #pragma unroll
  for (int i = 0; i < 2; i++)
    #pragma unroll
    for (int r = 0; r < 4; r++) {
      int row = i * 16 + rq + r;
      float gm = red[0][0][row];
      #pragma unroll
      for (int q = 1; q < 8; q++) gm = fmaxf(gm, red[0][q][row]);
      float s = 0.f;
      #pragma unroll
      for (int j = 0; j < 4; j++) {
        float e = __expf(acc2[i][j][r] - gm);
        acc2[i][j][r] = e;
        s += e;
      }
      rsum[i][r] = s;
    }
  #pragma unroll
  for (int s = 1; s < 16; s <<= 1)
    #pragma unroll
    for (int i = 0; i < 2; i++)
      #pragma unroll
      for (int r = 0; r < 4; r++)
        rsum[i][r] += __shfl_xor(rsum[i][r], s);
  if (col == 0)
    #pragma unroll
    for (int i = 0; i < 2; i++)
      #pragma unroll
      for (int r = 0; r < 4; r++) red[1][wave][i * 16 + rq + r] = rsum[i][r];
  __syncthreads();

  // each wave writes its own normalized 64-col P chunk
  #pragma unroll
  for (int i = 0; i < 2; i++)
    #pragma unroll
    for (int r = 0; r < 4; r++) {
      int row = i * 16 + rq + r;
      float tot = red[1][0][row];
      #pragma unroll
      for (int q = 1; q < 8; q++) tot += red[1][q][row];
      float inv = 1.f / tot;
      #pragma unroll
      for (int j = 0; j < 4; j++)
        tP[row][wave * 64 + j * 16 + col] = f2b(acc2[i][j][r] * inv);
    }
  __syncthreads();

  // ---- stage 3a: Z = P @ hnT^T (32 x 96), K = 512 ----
  // waves 0..3: both m-frags of n=wave; waves 4..7: one frag (m=w&1, n=(w>>1)+2)
  f32x4 z0 = (f32x4){0.f, 0.f, 0.f, 0.f}, z1 = z0;
  if (wave < 4) {
    int n = wave;
    #pragma unroll 4
    for (int kb = 0; kb < 512; kb += 32) {
      bf16x8 bv = *(const bf16x8*)(hTB + (size_t)(n * 16 + fm) * SEQ + kb + fq);
      bf16x8 af0 = *(const bf16x8*)&tP[fm][kb + fq];
      bf16x8 af1 = *(const bf16x8*)&tP[16 + fm][kb + fq];
      z0 = MFMA16(af0, bv, z0);
      z1 = MFMA16(af1, bv, z1);
    }
    #pragma unroll
    for (int r = 0; r < 4; r++) {
      Zs[rq + r][n * 16 + col] = f2b(z0[r]);
      Zs[16 + rq + r][n * 16 + col] = f2b(z1[r]);
    }
  } else {
    int mA = wave & 1, n = (wave >> 1) + 2;   // wave 4,5 -> n=4; 6,7 -> n=5
    #pragma unroll 4
    for (int kb = 0; kb < 512; kb += 32) {
      bf16x8 bv = *(const bf16x8*)(hTB + (size_t)(n * 16 + fm) * SEQ + kb + fq);
      bf16x8 af = *(const bf16x8*)&tP[mA * 16 + fm][kb + fq];
      z0 = MFMA16(af, bv, z0);
    }
    #pragma unroll
    for (int r = 0; r < 4; r++)
      Zs[mA * 16 + rq + r][n * 16 + col] = f2b(z0[r]);
  }
  __syncthreads();

  // ---- stage 3b: O = Z @ Gt^T (32 x 96); waves 0..5, 2 n-frags each ----
  if (wave < 6) {
    int mA = wave & 1, nb = wave >> 1;
    f32x4 o0 = (f32x4){0.f, 0.f, 0.f, 0.f}, o1 = o0;
    #pragma unroll
    for (int kb = 0; kb < 96; kb += 32) {
      bf16x8 af = *(const bf16x8*)&Zs[mA * 16 + fm][kb + fq];
      bf16x8 b0 = *(const bf16x8*)(GtH + (size_t)(nb * 16 + fm) * DIM + kb + fq);
      bf16x8 b1 = *(const bf16x8*)(GtH + (size_t)((nb + 3) * 16 + fm) * DIM + kb + fq);
      o0 = MFMA16(af, b0, o0);
      o1 = MFMA16(af, b1, o1);
    }
    #pragma unroll
    for (int r = 0; r < 4; r++) {
      int gr = b * SEQ + m0 + mA * 16 + rq + r;
      atomicAdd(x + (size_t)gr * DIM + nb * 16 + col, o0[r]);
      atomicAdd(x + (size_t)gr * DIM + (nb + 3) * 16 + col, o1[r]);
    }
  }
}

// ====== fused MLP (8 waves): [gmid-LN] + LN + GEMM1 + GELU + GEMM2 + res ====
// grid (32) x 512 threads; each block owns 32 rows. LN epilogue:
// lnmode 1 -> hn/hnT with gamma(lngb+lngoff); lnmode 2 -> final LN to dout.
__global__ __launch_bounds__(512) void fmlp_kernel(
    float* __restrict__ X,
    const void* __restrict__ gmidb, size_t gmidoff, int useMid,
    const void* __restrict__ gmb, size_t gmoff,
    const bf16* __restrict__ w1T,   // [384][96]
    const void* __restrict__ b1b, size_t b1off,
    const bf16* __restrict__ w2T,   // [96][384]
    const void* __restrict__ b2b, size_t b2off,
    int lnmode, const void* __restrict__ lngb, size_t lngoff,
    bf16* __restrict__ hn, bf16* __restrict__ hnT, void* __restrict__ dout,
    const int* __restrict__ flagp) {
  __shared__ float X1s[32][96];
  __shared__ bf16 As[32][104];
  __shared__ bf16 Hs[32][392];
  int f = *flagp;
  int tid = threadIdx.x, lane = tid & 63, wave = tid >> 6;  // 0..7
  int fm = lane & 15, fq = (lane >> 4) * 8;
  int col = lane & 15, rq = (lane >> 4) * 4;
  int m0 = blockIdx.x * 32;
  const char* gm = gptr(gmb, gmoff, f);
  float gm0 = gload(gm, lane, f) + 1.f;
  float gm1 = (lane < 32) ? (gload(gm, 64 + lane, f) + 1.f) : 0.f;
  float gd0 = 1.f, gd1 = 1.f;
  if (useMid) {
    const char* gmid = gptr(gmidb, gmidoff, f);
    gd0 = gload(gmid, lane, f) + 1.f;
    gd1 = (lane < 32) ? (gload(gmid, 64 + lane, f) + 1.f) : 0.f;
  }
  for (int r = wave; r < 32; r += 8) {
    const float* xr = X + (size_t)(m0 + r) * DIM;
    float v0 = xr[lane];
    float v1 = (lane < 32) ? xr[64 + lane] : 0.f;
    if (useMid) {
      float s = v0 + v1;
      #pragma unroll
      for (int off = 32; off > 0; off >>= 1) s += __shfl_xor(s, off);
      float mu = s * (1.f / 96.f);
      float d0 = v0 - mu;
      float d1 = (lane < 32) ? (v1 - mu) : 0.f;
      float q = d0 * d0 + d1 * d1;
      #pragma unroll
      for (int off = 32; off > 0; off >>= 1) q += __shfl_xor(q, off);
      float rstd = rsqrtf(q * (1.f / 96.f) + EPSLN);
      v0 = d0 * rstd * gd0;
      v1 = (lane < 32) ? (d1 * rstd * gd1) : 0.f;
    }
    X1s[r][lane] = v0;
    if (lane < 32) X1s[r][64 + lane] = v1;
    float s = v0 + v1;
    #pragma unroll
    for (int off = 32; off > 0; off >>= 1) s += __shfl_xor(s, off);
    float mu = s * (1.f / 96.f);
    float d0 = v0 - mu;
    float d1 = (lane < 32) ? (v1 - mu) : 0.f;
    float q = d0 * d0 + d1 * d1;
    #pragma unroll
    for (int off = 32; off > 0; off >>= 1) q += __shfl_xor(q, off);
    float rstd = rsqrtf(q * (1.f / 96.f) + EPSLN);
    As[r][lane] = f2b(d0 * rstd * gm0);
    if (lane < 32) As[r][64 + lane] = f2b(d1 * rstd * gm1);
  }
  __syncthreads();

  // ---- GEMM1: [32x96] @ W1 -> [32x384]; wave = (m, 96-col chunk) ----
  int mw = wave & 1, nh = wave >> 1;     // nh in 0..3: cols [nh*96, nh*96+96)
  f32x4 acc1[6];
  #pragma unroll
  for (int j = 0; j < 6; j++) acc1[j] = (f32x4){0.f, 0.f, 0.f, 0.f};
  #pragma unroll
  for (int kb = 0; kb < 96; kb += 32) {
    bf16x8 af = *(const bf16x8*)&As[mw * 16 + fm][kb + fq];
    #pragma unroll
    for (int j = 0; j < 6; j++) {
      bf16x8 bv = *(const bf16x8*)(w1T + (size_t)(nh * 96 + j * 16 + fm) * DIM + kb + fq);
      acc1[j] = MFMA16(af, bv, acc1[j]);
    }
  }
  const char* b1p = gptr(b1b, b1off, f);
  #pragma unroll
  for (int j = 0; j < 6; j++) {
    int gn = nh * 96 + j * 16 + col;
    float bv = gload(b1p, gn, f);
    #pragma unroll
    for (int r = 0; r < 4; r++) {
      float v = acc1[j][r] + bv;
      v = 0.5f * v * (1.f + erff(v * 0.70710678118f));
      Hs[mw * 16 + rq + r][gn] = f2b(v);
    }
  }
  __syncthreads();

  // ---- GEMM2: [32x384] @ W2 -> [32x96]; waves 0..5, 2 n-frags each ----
  if (wave < 6) {
    int mA = wave & 1, nb = wave >> 1;
    f32x4 o0 = (f32x4){0.f, 0.f, 0.f, 0.f}, o1 = o0;
    #pragma unroll 4
    for (int kb = 0; kb < 384; kb += 32) {
      bf16x8 af = *(const bf16x8*)&Hs[mA * 16 + fm][kb + fq];
      bf16x8 b0 = *(const bf16x8*)(w2T + (size_t)(nb * 16 + fm) * HIDN + kb + fq);
      bf16x8 b1 = *(const bf16x8*)(w2T + (size_t)((nb + 3) * 16 + fm) * HIDN + kb + fq);
      o0 = MFMA16(af, b0, o0);
      o1 = MFMA16(af, b1, o1);
    }
    const char* b2p = gptr(b2b, b2off, f);
    float bb0 = gload(b2p, nb * 16 + col, f);
    float bb1 = gload(b2p, (nb + 3) * 16 + col, f);
    #pragma unroll
    for (int r = 0; r < 4; r++) {
      int row = mA * 16 + rq + r;
      int gmr = m0 + row;
      X[(size_t)gmr * DIM + nb * 16 + col] = X1s[row][nb * 16 + col] + o0[r] + bb0;
      X[(size_t)gmr * DIM + (nb + 3) * 16 + col] = X1s[row][(nb + 3) * 16 + col] + o1[r] + bb1;
    }
  }
  __syncthreads();

  // ---- fused LN epilogue over this block's 32 rows ----
  const char* lg = gptr(lngb, lngoff, f);
  for (int r = wave; r < 32; r += 8) {
    int row = m0 + r;
    size_t base = (size_t)row * DIM;
    float v0 = X[base + lane];
    float v1 = (lane < 32) ? X[base + 64 + lane] : 0.f;
    float o0, o1;
    ln_row_vals(v0, v1, lane, lg, f, o0, o1);
    if (lnmode == 1) {
      store_hn(hn, hnT, row, lane, o0, o1);
    } else {
      if (!f) {
        ((float*)dout)[base + lane] = o0;
        if (lane < 32) ((float*)dout)[base + 64 + lane] = o1;
      } else {
        ((bf16*)dout)[base + lane] = f2b(o0);
        if (lane < 32) ((bf16*)dout)[base + 64 + lane] = f2b(o1);
      }
    }
  }
}

// ---------------- host-side orchestration ----------------
extern "C" void kernel_launch(void* const* d_in, const int* in_sizes, int n_in,
                              void* d_out, int out_size, void* d_ws, size_t ws_size,
                              hipStream_t stream) {
  const void* in_x    = d_in[0];
  const void* gam_a   = d_in[1];
  const void* Wq      = d_in[2];
  const void* Wk      = d_in[3];
  const void* Wv      = d_in[4];
  const void* Wo      = d_in[5];
  const void* gam_m   = d_in[6];
  const void* W1      = d_in[7];
  const void* b1      = d_in[8];
  const void* W2      = d_in[9];
  const void* b2      = d_in[10];
  const void* gam_mid = d_in[11];
  const void* gam_fin = d_in[12];

  char* wsb = (char*)d_ws;
  size_t off = 0;
  auto carve = [&](size_t bytes) {
    char* p = wsb + off;
    off += (bytes + 255) & ~(size_t)255;
    return p;
  };
  int*   flag = (int*)carve(256);
  float* x    = (float*)carve((size_t)TOK * DIM * 4);
  bf16*  hn   = (bf16*)carve((size_t)TOK * DIM * 2);
  bf16*  hnT  = (bf16*)carve((size_t)2 * DIM * SEQ * 2);
  const size_t WSZ = (size_t)15 * DIM * INNER;   // per big weight, elements
  bf16*  wqB  = (bf16*)carve(WSZ * 2);
  bf16*  wkB  = (bf16*)carve(WSZ * 2);
  bf16*  wvB  = (bf16*)carve(WSZ * 2);
  bf16*  woT  = (bf16*)carve(WSZ * 2);
  bf16*  w1T  = (bf16*)carve((size_t)10 * DIM * HIDN * 2);
  bf16*  w2T  = (bf16*)carve((size_t)10 * DIM * HIDN * 2);
  bf16*  Mt   = (bf16*)carve((size_t)120 * DIM * DIM * 2);
  bf16*  Gt   = (bf16*)carve((size_t)120 * DIM * DIM * 2);

  detect_kernel<<<dim3(1), dim3(256), 0, stream>>>(in_x, flag);

  // ---- once-per-call weight prep ----
  int nW = (int)WSZ;
  castw3_kernel<<<dim3((nW / 4 + 255) / 256, 3), dim3(256), 0, stream>>>(
      Wq, Wk, Wv, wqB, wkB, wvB, nW, flag);
  wtrans_kernel<<<dim3(2, 192, 15), dim3(256), 0, stream>>>(Wo, INNER, DIM, woT, flag);
  wtrans_kernel<<<dim3(6, 3, 10), dim3(256), 0, stream>>>(W1, DIM, HIDN, w1T, flag);
  wtrans_kernel<<<dim3(2, 12, 10), dim3(256), 0, stream>>>(W2, HIDN, DIM, w2T, flag);
  mtgt_kernel<<<dim3(1, 2, 240), dim3(256), 0, stream>>>(
      Wq, Wk, Wv, wqB, wkB, wvB, woT, Mt, Gt, flag);

  // stage 0: cast input + LN(gam_a[0,0]) -> x, hn, hnT
  castln_kernel<<<dim3(TOK / 4), dim3(256), 0, stream>>>(in_x, x, hn, hnT, gam_a, flag);

  auto attn = [&](int d, int j) {
    size_t gi = ((size_t)d * 3 + j);
    fattn4_kernel<<<dim3(16, 16), dim3(512), 0, stream>>>(
        hn, hnT, Mt + gi * 8 * DIM * DIM, Gt + gi * 8 * DIM * DIM, x);
  };

  for (int d = 0; d < NDEPTH; d++) {
    bool last = (d == NDEPTH - 1);
    attn(d, 0);
    // mlp0 + fused LN(gam_a[d,1]) -> hn/hnT for attn1
    fmlp_kernel<<<dim3(32), dim3(512), 0, stream>>>(
        x, nullptr, 0, 0,
        gam_m, (size_t)(d * 2 + 0) * DIM,
        w1T + (size_t)(d * 2 + 0) * DIM * HIDN, b1, (size_t)(d * 2 + 0) * HIDN,
        w2T + (size_t)(d * 2 + 0) * DIM * HIDN, b2, (size_t)(d * 2 + 0) * DIM,
        1, gam_a, (size_t)(d * 3 + 1) * DIM, hn, hnT, nullptr, flag);
    attn(d, 1);
    ln_kernel<<<dim3(TOK / 4), dim3(256), 0, stream>>>(
        x, hn, hnT, gam_a, (size_t)(d * 3 + 2) * DIM, flag);
    attn(d, 2);
    // mlp1 (includes bare mid-LN) + fused LN: next gam_a[.,0] or final -> dout
    fmlp_kernel<<<dim3(32), dim3(512), 0, stream>>>(
        x, gam_mid, (size_t)d * DIM, 1,
        gam_m, (size_t)(d * 2 + 1) * DIM,
        w1T + (size_t)(d * 2 + 1) * DIM * HIDN, b1, (size_t)(d * 2 + 1) * HIDN,
        w2T + (size_t)(d * 2 + 1) * DIM * HIDN, b2, (size_t)(d * 2 + 1) * DIM,
        last ? 2 : 1, last ? gam_fin : gam_a,
        last ? (size_t)0 : (size_t)((d + 1) * 3) * DIM,
        hn, hnT, d_out, flag);
  }
}